// Round 2
// baseline (2324.135 us; speedup 1.0000x reference)
//
#include <hip/hip_runtime.h>
#include <hip/hip_bf16.h>

// Problem constants (fixed by setup_inputs)
#define B_   4
#define N_   4096
#define KNN_ 32
#define KK_  64          // 2*k
#define MTOT 1048576     // B*N*KK
#define BN_EPS 1e-3f

typedef unsigned int u32;
typedef unsigned long long u64;

__device__ __forceinline__ float bf2f(__hip_bfloat16 h) { return __bfloat162float(h); }

// wave-synchronous LDS fence (single-wave comms; no cross-wave races by construction)
__device__ __forceinline__ void lds_fence() {
    __asm__ volatile("s_waitcnt lgkmcnt(0)" ::: "memory");
}

// ---------------------------------------------------------------------------
// K1: dual KNN. One wave per query row; exact 24-bit radix select (index
// tie-break) over d2 keys recomputed deterministically each scan.
// grid: 512 blocks = 2 pairs * 4 batches * 64 row-chunks; 16 rows/wave.
// ---------------------------------------------------------------------------
__global__ __launch_bounds__(256) void knn_kernel(
    const float* __restrict__ p1, const float* __restrict__ p2,
    float* __restrict__ feats, float* __restrict__ grouped)
{
    __shared__ float cx[N_], cy[N_], cz[N_];     // 48 KB candidate coords
    __shared__ u32 hist[4][256];                 // per-wave histograms
    __shared__ u32 list_[4][64];                 // per-wave boundary list
    __shared__ u32 wcnt[4], lcnt[4];

    const int tid  = threadIdx.x;
    const int wave = tid >> 6, lane = tid & 63;
    const int pb   = blockIdx.x >> 6;            // 0..7
    const int pr   = pb >> 2, b = pb & 3;
    const int nbase = (blockIdx.x & 63) * 64;

    const float* src = pr ? p2 : p1;
    // stage candidate cloud for (pr,b)
    for (int i = tid; i < 3 * N_; i += 256) {
        int d = i >> 12, n = i & (N_ - 1);
        float v = src[(size_t)b * 3 * N_ + i];
        if (d == 0) cx[n] = v; else if (d == 1) cy[n] = v; else cz[n] = v;
    }
    __syncthreads();

    for (int r = 0; r < 16; ++r) {
        const int n = nbase + wave * 16 + r;
        float qx, qy, qz;
        if (pr == 0) { qx = cx[n]; qy = cy[n]; qz = cz[n]; }
        else {
            qx = p1[(size_t)b*3*N_ + n];
            qy = p1[(size_t)b*3*N_ + N_ + n];
            qz = p1[(size_t)b*3*N_ + 2*N_ + n];
        }
        const float s1 = fmaf(qx,qx, fmaf(qy,qy, qz*qz));

        // deterministic key of candidate c (identical FP ops at every scan)
        auto keyAt = [&](int c) -> u32 {
            float dx = cx[c], dy = cy[c], dz = cz[c];
            float s2c = fmaf(dx,dx, fmaf(dy,dy, dz*dz));
            float dot = fmaf(qx,dx, fmaf(qy,dy, qz*dz));
            float d2  = s1 + s2c - 2.0f*dot;
            u32 u = __float_as_uint(d2);
            return u ^ (u32)(((int)u >> 31) | 0x80000000);
        };

        u32 pfx = 0; int cprev = 0;
        for (int pass = 0; pass < 3; ++pass) {
            const int shift = 24 - 8 * pass;
            for (int i2 = lane; i2 < 256; i2 += 64) hist[wave][i2] = 0;
            lds_fence();
            const int psh = (32 - 8 * pass) & 31;   // prefix shift (pass>0)
            for (int j = 0; j < 64; ++j) {
                int c = j * 64 + lane;
                u32 key = keyAt(c);
                bool match = (pass == 0) || ((key >> psh) == pfx);
                if (match) atomicAdd(&hist[wave][(key >> shift) & 255u], 1u);
            }
            lds_fence();
            // wave-level scan of 256 bins (lane owns bins 4l..4l+3)
            int h0 = (int)hist[wave][4*lane+0], h1 = (int)hist[wave][4*lane+1];
            int h2 = (int)hist[wave][4*lane+2], h3 = (int)hist[wave][4*lane+3];
            int ltot = h0 + h1 + h2 + h3;
            int incl = ltot;
            #pragma unroll
            for (int off = 1; off < 64; off <<= 1) {
                int v = __shfl_up(incl, off, 64);
                if (lane >= off) incl += v;
            }
            int excl = incl - ltot;
            const int rt = 31 - cprev;
            int e0 = excl, e1 = e0 + h0, e2 = e1 + h1, e3 = e2 + h2;
            int fbin = -1, fbelow = 0;
            if      (rt >= e0 && rt < e0 + h0) { fbin = 4*lane+0; fbelow = e0; }
            else if (rt >= e1 && rt < e1 + h1) { fbin = 4*lane+1; fbelow = e1; }
            else if (rt >= e2 && rt < e2 + h2) { fbin = 4*lane+2; fbelow = e2; }
            else if (rt >= e3 && rt < e3 + h3) { fbin = 4*lane+3; fbelow = e3; }
            u64 bal = __ballot(fbin >= 0);
            int srcl = (int)__builtin_ctzll(bal);
            fbin   = __shfl(fbin, srcl, 64);
            fbelow = __shfl(fbelow, srcl, 64);
            pfx = (pfx << 8) | (u32)fbin;
            cprev += fbelow;
        }

        auto emit = [&](int c, int slot) {
            float dx = cx[c], dy = cy[c], dz = cz[c];
            float rx = dx - qx, ry = dy - qy, rz = dz - qz;
            float dist = sqrtf(fmaf(rx,rx, fmaf(ry,ry, rz*rz)));
            size_t base = ((size_t)(b * N_ + n) * KK_ + pr * KNN_ + slot);
            *(float4*)(feats + base * 4) = make_float4(rx, ry, rz, dist);
            grouped[base*3 + 0] = dx; grouped[base*3 + 1] = dy; grouped[base*3 + 2] = dz;
        };

        if (lane == 0) { wcnt[wave] = 0; lcnt[wave] = 0; }
        lds_fence();
        for (int j = 0; j < 64; ++j) {
            int c = j * 64 + lane;
            u32 key = keyAt(c);
            u32 top = key >> 8;
            if (top < pfx) {
                u32 s = atomicAdd(&wcnt[wave], 1u);
                emit(c, (int)s);
            } else if (top == pfx) {
                u32 li = atomicAdd(&lcnt[wave], 1u);
                if (li < 64) list_[wave][li] = ((key & 255u) << 12) | (u32)c;
            }
        }
        lds_fence();
        int m = min((int)lcnt[wave], 64);
        int need = 32 - cprev;
        if (lane < m) {
            u32 e = list_[wave][lane];
            int rank = 0;
            for (int t2 = 0; t2 < m; ++t2) rank += (list_[wave][t2] < e) ? 1 : 0;
            if (rank < need) emit((int)(e & 4095u), cprev + rank);
        }
        lds_fence();
    }
}

// ---------------------------------------------------------------------------
// K2: stats of y1 = W1@feat + b1 (per-channel sum / sumsq over 1M positions)
// grid: 1024 blocks * 1024 positions each
// ---------------------------------------------------------------------------
__global__ __launch_bounds__(256) void stats1_kernel(
    const float* __restrict__ feats,
    const float* __restrict__ W1, const float* __restrict__ b1,
    float* __restrict__ s1S, float* __restrict__ s1Q)
{
    __shared__ float4 featL[256];
    __shared__ float red[512];
    const int tid = threadIdx.x;
    const int ch = tid & 63, pg = tid >> 6;
    float w0 = W1[ch*4+0], w1v = W1[ch*4+1];
    float w2v = W1[ch*4+2], w3v = W1[ch*4+3];
    float bb = b1[ch];
    float sum = 0.f, sq = 0.f;
    for (int chunk = 0; chunk < 4; ++chunk) {
        __syncthreads();
        size_t pbase = (size_t)blockIdx.x * 1024 + (size_t)chunk * 256;
        featL[tid] = ((const float4*)feats)[pbase + tid];
        __syncthreads();
        for (int i = 0; i < 64; ++i) {
            float4 f = featL[pg * 64 + i];
            float y = bb + w0*f.x + w1v*f.y + w2v*f.z + w3v*f.w;
            sum += y; sq += y * y;
        }
    }
    red[tid] = sum; red[256 + tid] = sq;
    __syncthreads();
    if (tid < 64) {
        float s = red[tid] + red[64+tid] + red[128+tid] + red[192+tid];
        float q = red[256+tid] + red[320+tid] + red[384+tid] + red[448+tid];
        atomicAdd(&s1S[tid], s);
        atomicAdd(&s1Q[tid], q);
    }
}

// ---------------------------------------------------------------------------
// K3: per-row: conv1+bn1+relu -> x2, conv2 -> y2 (stored bf16) + stats2.
// grid: 1024 blocks * 16 rows. thread = (kk = tid&63, cg = tid>>6).
// ---------------------------------------------------------------------------
__global__ __launch_bounds__(256) void conv2_kernel(
    const float* __restrict__ feats,
    const float* __restrict__ W1, const float* __restrict__ b1g,
    const float* __restrict__ g1, const float* __restrict__ be1,
    const float* __restrict__ W2, const float* __restrict__ b2g,
    const float* __restrict__ s1S, const float* __restrict__ s1Q,
    __hip_bfloat16* __restrict__ y2g, float* __restrict__ s2S, float* __restrict__ s2Q)
{
    __shared__ float  w2L[64 * 64];   // 16 KB
    __shared__ float  x2L[64 * 64];   // 16 KB
    __shared__ float4 w1L[64];
    __shared__ float4 featR[64];
    __shared__ float  sc1[64], c1s[64], b2L[64];
    __shared__ float  statS[64], statQ[64];

    const int tid = threadIdx.x, lane = tid & 63;
    const int kk = tid & 63, cg = tid >> 6;
    for (int i = tid; i < 4096; i += 256) w2L[i] = W2[i];
    if (tid < 64) {
        w1L[tid] = make_float4(W1[tid*4+0], W1[tid*4+1], W1[tid*4+2], W1[tid*4+3]);
        float m  = s1S[tid] * (1.0f / MTOT);
        float v  = s1Q[tid] * (1.0f / MTOT) - m * m;
        float rs = rsqrtf(v + BN_EPS);
        float sc = g1[tid] * rs;
        sc1[tid] = sc;
        c1s[tid] = be1[tid] - sc * m + sc * b1g[tid];
        b2L[tid] = b2g[tid];
        statS[tid] = 0.f; statQ[tid] = 0.f;
    }
    __syncthreads();

    for (int r = 0; r < 16; ++r) {
        const size_t row = (size_t)blockIdx.x * 16 + r;
        ((float*)featR)[tid] = feats[row * 256 + tid];
        __syncthreads();
        // x2 = relu(bn1(conv1))
        float4 f = featR[kk];
        for (int i = 0; i < 16; ++i) {
            int ci = cg * 16 + i;
            float4 w = w1L[ci];
            float y = w.x*f.x + w.y*f.y + w.z*f.z + w.w*f.w;
            x2L[ci * 64 + kk] = fmaxf(sc1[ci] * y + c1s[ci], 0.f);
        }
        __syncthreads();
        // conv2: 16 output channels per thread
        float accs[16];
        #pragma unroll
        for (int j = 0; j < 16; ++j) accs[j] = 0.f;
        for (int ci4 = 0; ci4 < 16; ++ci4) {
            float xv0 = x2L[(ci4*4+0)*64 + kk];
            float xv1 = x2L[(ci4*4+1)*64 + kk];
            float xv2 = x2L[(ci4*4+2)*64 + kk];
            float xv3 = x2L[(ci4*4+3)*64 + kk];
            #pragma unroll
            for (int j = 0; j < 16; ++j) {
                float4 w = ((const float4*)w2L)[(cg*16+j)*16 + ci4];
                accs[j] += w.x*xv0 + w.y*xv1 + w.z*xv2 + w.w*xv3;
            }
        }
        #pragma unroll
        for (int j = 0; j < 16; ++j) {
            int co = cg * 16 + j;
            float y = accs[j] + b2L[co];
            y2g[(row * 64 + co) * 64 + kk] = __float2bfloat16(y);
            float sy = y, sqv = y * y;
            #pragma unroll
            for (int off = 1; off < 64; off <<= 1) {
                sy  += __shfl_xor(sy,  off, 64);
                sqv += __shfl_xor(sqv, off, 64);
            }
            if (lane == 0) { atomicAdd(&statS[co], sy); atomicAdd(&statQ[co], sqv); }
        }
        __syncthreads();
    }
    if (tid < 64) { atomicAdd(&s2S[tid], statS[tid]); atomicAdd(&s2Q[tid], statQ[tid]); }
}

// ---------------------------------------------------------------------------
// K4/K5: per-row bn2+relu -> x3, conv3. FINAL=false: stats3 only.
// FINAL=true: bn3 -> channel max -> relu -> softmax -> weighted sum -> out.
// grid: 1024 blocks * 16 rows.
// ---------------------------------------------------------------------------
template<bool FINAL>
__global__ __launch_bounds__(256) void conv3_kernel(
    const __hip_bfloat16* __restrict__ y2g,
    const float* __restrict__ g2, const float* __restrict__ be2,
    const float* __restrict__ W3, const float* __restrict__ b3g,
    const float* __restrict__ g3, const float* __restrict__ be3,
    const float* __restrict__ s2S, const float* __restrict__ s2Q,
    float* __restrict__ s3S, float* __restrict__ s3Q,
    const float* __restrict__ grouped, float* __restrict__ outp)
{
    __shared__ float w3L[128 * 64];   // 32 KB
    __shared__ float x3L[64 * 64];    // 16 KB
    __shared__ float sc2[64], sh2[64];
    __shared__ float sc3[128], sh3[128], b3L[128];
    __shared__ float statS[128], statQ[128];
    __shared__ float scoreL[4 * 64];

    const int tid = threadIdx.x, lane = tid & 63;
    const int kk = tid & 63, cg = tid >> 6;
    for (int i = tid; i < 128 * 64; i += 256) w3L[i] = W3[i];
    if (tid < 64) {
        float m  = s2S[tid] * (1.0f / MTOT);
        float v  = s2Q[tid] * (1.0f / MTOT) - m * m;
        float rs = rsqrtf(v + BN_EPS);
        float sc = g2[tid] * rs;
        sc2[tid] = sc; sh2[tid] = be2[tid] - sc * m;
    }
    if (tid < 128) {
        b3L[tid] = b3g[tid];
        statS[tid] = 0.f; statQ[tid] = 0.f;
        if (FINAL) {
            float m  = s3S[tid] * (1.0f / MTOT);
            float v  = s3Q[tid] * (1.0f / MTOT) - m * m;
            float rs = rsqrtf(v + BN_EPS);
            float sc = g3[tid] * rs;
            sc3[tid] = sc; sh3[tid] = be3[tid] - sc * m;
        }
    }
    __syncthreads();

    for (int r = 0; r < 16; ++r) {
        const size_t row = (size_t)blockIdx.x * 16 + r;
        for (int i = 0; i < 16; ++i) {
            int li = tid + i * 256;
            int ci = li >> 6;
            float y = bf2f(y2g[row * 4096 + li]);
            x3L[li] = fmaxf(sc2[ci] * y + sh2[ci], 0.f);
        }
        __syncthreads();
        float accs[32];
        #pragma unroll
        for (int j = 0; j < 32; ++j) accs[j] = 0.f;
        for (int ci4 = 0; ci4 < 16; ++ci4) {
            float xv0 = x3L[(ci4*4+0)*64 + kk];
            float xv1 = x3L[(ci4*4+1)*64 + kk];
            float xv2 = x3L[(ci4*4+2)*64 + kk];
            float xv3 = x3L[(ci4*4+3)*64 + kk];
            #pragma unroll
            for (int j = 0; j < 32; ++j) {
                float4 w = ((const float4*)w3L)[(cg*32+j)*16 + ci4];
                accs[j] += w.x*xv0 + w.y*xv1 + w.z*xv2 + w.w*xv3;
            }
        }
        if (!FINAL) {
            #pragma unroll
            for (int j = 0; j < 32; ++j) {
                int co = cg * 32 + j;
                float y = accs[j] + b3L[co];
                float sy = y, sq = y * y;
                #pragma unroll
                for (int off = 1; off < 64; off <<= 1) {
                    sy += __shfl_xor(sy, off, 64);
                    sq += __shfl_xor(sq, off, 64);
                }
                if (lane == 0) { atomicAdd(&statS[co], sy); atomicAdd(&statQ[co], sq); }
            }
            __syncthreads();
        } else {
            float smax = -1e30f;
            #pragma unroll
            for (int j = 0; j < 32; ++j) {
                int co = cg * 32 + j;
                float z = sc3[co] * (accs[j] + b3L[co]) + sh3[co];
                smax = fmaxf(smax, z);
            }
            scoreL[cg * 64 + kk] = smax;
            __syncthreads();
            if (tid < 64) {
                float sc = fmaxf(fmaxf(scoreL[kk], scoreL[64+kk]),
                                 fmaxf(scoreL[128+kk], scoreL[192+kk]));
                sc = fmaxf(sc, 0.f);   // relu before channel-max is equivalent post-max
                float mx = sc;
                #pragma unroll
                for (int off = 1; off < 64; off <<= 1) mx = fmaxf(mx, __shfl_xor(mx, off, 64));
                float e = __expf(sc - mx);
                float se = e;
                #pragma unroll
                for (int off = 1; off < 64; off <<= 1) se += __shfl_xor(se, off, 64);
                float w = e / se;
                float gx = grouped[(row*64 + kk)*3 + 0];
                float gy = grouped[(row*64 + kk)*3 + 1];
                float gz = grouped[(row*64 + kk)*3 + 2];
                float ox = w * gx, oy = w * gy, oz = w * gz;
                #pragma unroll
                for (int off = 1; off < 64; off <<= 1) {
                    ox += __shfl_xor(ox, off, 64);
                    oy += __shfl_xor(oy, off, 64);
                    oz += __shfl_xor(oz, off, 64);
                }
                if (lane == 0) {
                    int bb = (int)(row >> 12), n = (int)(row & 4095);
                    outp[(size_t)bb * 3 * N_ + 0 * N_ + n] = ox;
                    outp[(size_t)bb * 3 * N_ + 1 * N_ + n] = oy;
                    outp[(size_t)bb * 3 * N_ + 2 * N_ + n] = oz;
                }
            }
            __syncthreads();
        }
    }
    if (!FINAL) {
        if (tid < 128) { atomicAdd(&s3S[tid], statS[tid]); atomicAdd(&s3Q[tid], statQ[tid]); }
    }
}

// ---------------------------------------------------------------------------
extern "C" void kernel_launch(void* const* d_in, const int* in_sizes, int n_in,
                              void* d_out, int out_size, void* d_ws, size_t ws_size,
                              hipStream_t stream)
{
    const float* p1  = (const float*)d_in[0];
    const float* p2  = (const float*)d_in[1];
    // d_in[2] = k (always 32), d_in[3] = t (unused by reference)
    const float* W1  = (const float*)d_in[4];
    const float* b1  = (const float*)d_in[5];
    const float* g1  = (const float*)d_in[6];
    const float* be1 = (const float*)d_in[7];
    const float* W2  = (const float*)d_in[8];
    const float* b2  = (const float*)d_in[9];
    const float* g2  = (const float*)d_in[10];
    const float* be2 = (const float*)d_in[11];
    const float* W3  = (const float*)d_in[12];
    const float* b3  = (const float*)d_in[13];
    const float* g3  = (const float*)d_in[14];
    const float* be3 = (const float*)d_in[15];

    char* ws = (char*)d_ws;
    const size_t OFF_FEATS   = 4096;
    const size_t OFF_GROUPED = OFF_FEATS + (size_t)MTOT * 4 * 4;        // 16 MB feats
    const size_t OFF_Y2      = OFF_GROUPED + (size_t)MTOT * 3 * 4;      // 12 MB grouped
    const size_t NEEDED      = OFF_Y2 + (size_t)MTOT * 64 * 2;          // 128 MB y2 bf16
    if (ws_size < NEEDED) return;  // fail visibly (wrong output) rather than fault

    float* s1S = (float*)(ws + 0);    float* s1Q = (float*)(ws + 256);
    float* s2S = (float*)(ws + 512);  float* s2Q = (float*)(ws + 768);
    float* s3S = (float*)(ws + 1024); float* s3Q = (float*)(ws + 1536);
    float* feats   = (float*)(ws + OFF_FEATS);
    float* grouped = (float*)(ws + OFF_GROUPED);
    __hip_bfloat16* y2g = (__hip_bfloat16*)(ws + OFF_Y2);

    hipMemsetAsync(ws, 0, 2048, stream);  // zero all stats accumulators

    knn_kernel<<<512, 256, 0, stream>>>(p1, p2, feats, grouped);
    stats1_kernel<<<1024, 256, 0, stream>>>(feats, W1, b1, s1S, s1Q);
    conv2_kernel<<<1024, 256, 0, stream>>>(feats, W1, b1, g1, be1, W2, b2,
                                           s1S, s1Q, y2g, s2S, s2Q);
    conv3_kernel<false><<<1024, 256, 0, stream>>>(y2g, g2, be2, W3, b3, g3, be3,
                                                  s2S, s2Q, s3S, s3Q, nullptr, nullptr);
    conv3_kernel<true><<<1024, 256, 0, stream>>>(y2g, g2, be2, W3, b3, g3, be3,
                                                 s2S, s2Q, s3S, s3Q, grouped,
                                                 (float*)d_out);
}

// Round 3
// 902.518 us; speedup vs baseline: 2.5752x; 2.5752x over previous
//
#include <hip/hip_runtime.h>
#include <hip/hip_bf16.h>

// Problem constants (fixed by setup_inputs)
#define B_   4
#define N_   4096
#define KNN_ 32
#define KK_  64          // 2*k
#define MTOT 1048576     // B*N*KK
#define BN_EPS 1e-3f

typedef unsigned int u32;
typedef unsigned long long u64;
typedef __attribute__((ext_vector_type(8))) short bf16x8;
typedef __attribute__((ext_vector_type(4))) float f32x4;

__device__ __forceinline__ float bfu2f(u32 u) { return __uint_as_float(u << 16); }
__device__ __forceinline__ ushort f2bf_bits(float f) {   // RNE, finite inputs only
    u32 b = __float_as_uint(f);
    b += 0x7fffu + ((b >> 16) & 1u);
    return (ushort)(b >> 16);
}

// wave-synchronous LDS fence (single-wave comms; no cross-wave races by construction)
__device__ __forceinline__ void lds_fence() {
    __asm__ volatile("s_waitcnt lgkmcnt(0)" ::: "memory");
}

// ---------------------------------------------------------------------------
// K1: dual KNN (unchanged from round 2 — correct; optimize next round).
// ---------------------------------------------------------------------------
__global__ __launch_bounds__(256) void knn_kernel(
    const float* __restrict__ p1, const float* __restrict__ p2,
    float* __restrict__ feats, float* __restrict__ grouped)
{
    __shared__ float cx[N_], cy[N_], cz[N_];
    __shared__ u32 hist[4][256];
    __shared__ u32 list_[4][64];
    __shared__ u32 wcnt[4], lcnt[4];

    const int tid  = threadIdx.x;
    const int wave = tid >> 6, lane = tid & 63;
    const int pb   = blockIdx.x >> 6;
    const int pr   = pb >> 2, b = pb & 3;
    const int nbase = (blockIdx.x & 63) * 64;

    const float* src = pr ? p2 : p1;
    for (int i = tid; i < 3 * N_; i += 256) {
        int d = i >> 12, n = i & (N_ - 1);
        float v = src[(size_t)b * 3 * N_ + i];
        if (d == 0) cx[n] = v; else if (d == 1) cy[n] = v; else cz[n] = v;
    }
    __syncthreads();

    for (int r = 0; r < 16; ++r) {
        const int n = nbase + wave * 16 + r;
        float qx, qy, qz;
        if (pr == 0) { qx = cx[n]; qy = cy[n]; qz = cz[n]; }
        else {
            qx = p1[(size_t)b*3*N_ + n];
            qy = p1[(size_t)b*3*N_ + N_ + n];
            qz = p1[(size_t)b*3*N_ + 2*N_ + n];
        }
        const float s1 = fmaf(qx,qx, fmaf(qy,qy, qz*qz));

        auto keyAt = [&](int c) -> u32 {
            float dx = cx[c], dy = cy[c], dz = cz[c];
            float s2c = fmaf(dx,dx, fmaf(dy,dy, dz*dz));
            float dot = fmaf(qx,dx, fmaf(qy,dy, qz*dz));
            float d2  = s1 + s2c - 2.0f*dot;
            u32 u = __float_as_uint(d2);
            return u ^ (u32)(((int)u >> 31) | 0x80000000);
        };

        u32 pfx = 0; int cprev = 0;
        for (int pass = 0; pass < 3; ++pass) {
            const int shift = 24 - 8 * pass;
            for (int i2 = lane; i2 < 256; i2 += 64) hist[wave][i2] = 0;
            lds_fence();
            const int psh = (32 - 8 * pass) & 31;
            for (int j = 0; j < 64; ++j) {
                int c = j * 64 + lane;
                u32 key = keyAt(c);
                bool match = (pass == 0) || ((key >> psh) == pfx);
                if (match) atomicAdd(&hist[wave][(key >> shift) & 255u], 1u);
            }
            lds_fence();
            int h0 = (int)hist[wave][4*lane+0], h1 = (int)hist[wave][4*lane+1];
            int h2 = (int)hist[wave][4*lane+2], h3 = (int)hist[wave][4*lane+3];
            int ltot = h0 + h1 + h2 + h3;
            int incl = ltot;
            #pragma unroll
            for (int off = 1; off < 64; off <<= 1) {
                int v = __shfl_up(incl, off, 64);
                if (lane >= off) incl += v;
            }
            int excl = incl - ltot;
            const int rt = 31 - cprev;
            int e0 = excl, e1 = e0 + h0, e2 = e1 + h1, e3 = e2 + h2;
            int fbin = -1, fbelow = 0;
            if      (rt >= e0 && rt < e0 + h0) { fbin = 4*lane+0; fbelow = e0; }
            else if (rt >= e1 && rt < e1 + h1) { fbin = 4*lane+1; fbelow = e1; }
            else if (rt >= e2 && rt < e2 + h2) { fbin = 4*lane+2; fbelow = e2; }
            else if (rt >= e3 && rt < e3 + h3) { fbin = 4*lane+3; fbelow = e3; }
            u64 bal = __ballot(fbin >= 0);
            int srcl = (int)__builtin_ctzll(bal);
            fbin   = __shfl(fbin, srcl, 64);
            fbelow = __shfl(fbelow, srcl, 64);
            pfx = (pfx << 8) | (u32)fbin;
            cprev += fbelow;
        }

        auto emit = [&](int c, int slot) {
            float dx = cx[c], dy = cy[c], dz = cz[c];
            float rx = dx - qx, ry = dy - qy, rz = dz - qz;
            float dist = sqrtf(fmaf(rx,rx, fmaf(ry,ry, rz*rz)));
            size_t base = ((size_t)(b * N_ + n) * KK_ + pr * KNN_ + slot);
            *(float4*)(feats + base * 4) = make_float4(rx, ry, rz, dist);
            grouped[base*3 + 0] = dx; grouped[base*3 + 1] = dy; grouped[base*3 + 2] = dz;
        };

        if (lane == 0) { wcnt[wave] = 0; lcnt[wave] = 0; }
        lds_fence();
        for (int j = 0; j < 64; ++j) {
            int c = j * 64 + lane;
            u32 key = keyAt(c);
            u32 top = key >> 8;
            if (top < pfx) {
                u32 s = atomicAdd(&wcnt[wave], 1u);
                emit(c, (int)s);
            } else if (top == pfx) {
                u32 li = atomicAdd(&lcnt[wave], 1u);
                if (li < 64) list_[wave][li] = ((key & 255u) << 12) | (u32)c;
            }
        }
        lds_fence();
        int m = min((int)lcnt[wave], 64);
        int need = 32 - cprev;
        if (lane < m) {
            u32 e = list_[wave][lane];
            int rank = 0;
            for (int t2 = 0; t2 < m; ++t2) rank += (list_[wave][t2] < e) ? 1 : 0;
            if (rank < need) emit((int)(e & 4095u), cprev + rank);
        }
        lds_fence();
    }
}

// ---------------------------------------------------------------------------
// K2: stats of y1 = W1@feat + b1 (unchanged)
// ---------------------------------------------------------------------------
__global__ __launch_bounds__(256) void stats1_kernel(
    const float* __restrict__ feats,
    const float* __restrict__ W1, const float* __restrict__ b1,
    float* __restrict__ s1S, float* __restrict__ s1Q)
{
    __shared__ float4 featL[256];
    __shared__ float red[512];
    const int tid = threadIdx.x;
    const int ch = tid & 63, pg = tid >> 6;
    float w0 = W1[ch*4+0], w1v = W1[ch*4+1];
    float w2v = W1[ch*4+2], w3v = W1[ch*4+3];
    float bb = b1[ch];
    float sum = 0.f, sq = 0.f;
    for (int chunk = 0; chunk < 4; ++chunk) {
        __syncthreads();
        size_t pbase = (size_t)blockIdx.x * 1024 + (size_t)chunk * 256;
        featL[tid] = ((const float4*)feats)[pbase + tid];
        __syncthreads();
        for (int i = 0; i < 64; ++i) {
            float4 f = featL[pg * 64 + i];
            float y = bb + w0*f.x + w1v*f.y + w2v*f.z + w3v*f.w;
            sum += y; sq += y * y;
        }
    }
    red[tid] = sum; red[256 + tid] = sq;
    __syncthreads();
    if (tid < 64) {
        float s = red[tid] + red[64+tid] + red[128+tid] + red[192+tid];
        float q = red[256+tid] + red[320+tid] + red[384+tid] + red[448+tid];
        atomicAdd(&s1S[tid], s);
        atomicAdd(&s1Q[tid], q);
    }
}

// ---------------------------------------------------------------------------
// K3: MFMA conv2. Wave = (row, ptile of 16 positions), full 64 output ch.
// x2 = relu(bn1(conv1(feats))) computed per-lane in B-fragment layout;
// y2 = W2@x2 (bias dropped — cancels in BN2) stored bf16 in fragment-friendly
// layout: E(r,w,i,ci) = r*4096 + w*1024 + (ci>>2)*64 + i*4 + (ci&3).
// Stats2 (raw sums) accumulated in registers, reduced via xor-shuffle.
// ---------------------------------------------------------------------------
__global__ __launch_bounds__(256) void conv2_mfma(
    const float* __restrict__ feats,
    const float* __restrict__ W1, const float* __restrict__ b1,
    const float* __restrict__ g1, const float* __restrict__ be1,
    const float* __restrict__ W2,
    const float* __restrict__ s1S, const float* __restrict__ s1Q,
    ushort* __restrict__ y2F, float* __restrict__ s2S, float* __restrict__ s2Q)
{
    __shared__ float statS[64], statQ[64];
    const int tid = threadIdx.x;
    const int wid = tid >> 6, l = tid & 63, q = l >> 4, i = l & 15;
    if (tid < 64) { statS[tid] = 0.f; statQ[tid] = 0.f; }

    // per-lane folded conv1+bn1: x2[ci] = relu(w1f[ci].f + c1v[ci]), ci = h*32+q*8+j
    float4 w1f[16];
    float  c1v[16];
    #pragma unroll
    for (int h = 0; h < 2; ++h)
      #pragma unroll
      for (int j = 0; j < 8; ++j) {
        int ci = h*32 + q*8 + j;
        float m  = s1S[ci] * (1.0f / MTOT);
        float v  = s1Q[ci] * (1.0f / MTOT) - m * m;
        float sc = g1[ci] * rsqrtf(v + BN_EPS);
        w1f[h*8+j] = make_float4(sc*W1[ci*4+0], sc*W1[ci*4+1], sc*W1[ci*4+2], sc*W1[ci*4+3]);
        c1v[h*8+j] = fmaf(sc, b1[ci] - m, be1[ci]);
      }
    // A-fragments of W2: A[m=i][k=q*8+j] per (co-tile t, k-half h)
    bf16x8 a2[4][2];
    #pragma unroll
    for (int t = 0; t < 4; ++t)
      #pragma unroll
      for (int h = 0; h < 2; ++h)
        #pragma unroll
        for (int j = 0; j < 8; ++j)
          a2[t][h][j] = (short)f2bf_bits(W2[(t*16 + i)*64 + h*32 + q*8 + j]);

    float ssum[16], ssq[16];
    #pragma unroll
    for (int s = 0; s < 16; ++s) { ssum[s] = 0.f; ssq[s] = 0.f; }
    __syncthreads();

    for (int r16 = 0; r16 < 16; ++r16) {
        const int row = blockIdx.x * 16 + r16;
        float4 f = ((const float4*)feats)[row*64 + wid*16 + i];
        bf16x8 xb[2];
        #pragma unroll
        for (int h = 0; h < 2; ++h)
          #pragma unroll
          for (int j = 0; j < 8; ++j) {
            float4 w = w1f[h*8+j];
            float x = fmaxf(fmaf(w.x, f.x, fmaf(w.y, f.y, fmaf(w.z, f.z, fmaf(w.w, f.w, c1v[h*8+j])))), 0.f);
            xb[h][j] = (short)f2bf_bits(x);
          }
        f32x4 acc[4];
        #pragma unroll
        for (int t = 0; t < 4; ++t) acc[t] = (f32x4){0.f,0.f,0.f,0.f};
        #pragma unroll
        for (int t = 0; t < 4; ++t) {
            acc[t] = __builtin_amdgcn_mfma_f32_16x16x32_bf16(a2[t][0], xb[0], acc[t], 0, 0, 0);
            acc[t] = __builtin_amdgcn_mfma_f32_16x16x32_bf16(a2[t][1], xb[1], acc[t], 0, 0, 0);
        }
        ushort* wp = y2F + row*4096 + wid*1024 + q*64 + i*4;
        #pragma unroll
        for (int t = 0; t < 4; ++t) {
            #pragma unroll
            for (int reg = 0; reg < 4; ++reg) {
                float y = acc[t][reg];
                ssum[t*4+reg] += y;
                ssq[t*4+reg]  = fmaf(y, y, ssq[t*4+reg]);
            }
            uint2 pk;
            pk.x = (u32)f2bf_bits(acc[t][0]) | ((u32)f2bf_bits(acc[t][1]) << 16);
            pk.y = (u32)f2bf_bits(acc[t][2]) | ((u32)f2bf_bits(acc[t][3]) << 16);
            *(uint2*)(wp + t*256) = pk;
        }
    }
    // reduce over the 16 position-columns (xor within quad-preserving group)
    #pragma unroll
    for (int s = 0; s < 16; ++s) {
        #pragma unroll
        for (int off = 1; off < 16; off <<= 1) {
            ssum[s] += __shfl_xor(ssum[s], off, 64);
            ssq[s]  += __shfl_xor(ssq[s],  off, 64);
        }
    }
    if (i == 0) {
        #pragma unroll
        for (int s = 0; s < 16; ++s) {
            int co = (s >> 2)*16 + q*4 + (s & 3);
            atomicAdd(&statS[co], ssum[s]);
            atomicAdd(&statQ[co], ssq[s]);
        }
    }
    __syncthreads();
    if (tid < 64) { atomicAdd(&s2S[tid], statS[tid]); atomicAdd(&s2Q[tid], statQ[tid]); }
}

// ---------------------------------------------------------------------------
// K4/K5: MFMA conv3. Wave = (row, ptile), full 128 output ch.
// x3 = relu(bn2(y2)) built per-lane from y2F via 4× 8-B global loads.
// FINAL=false: accumulate raw stats3. FINAL=true: bn3 -> max -> relu ->
// softmax -> weighted sum of grouped -> out.
// ---------------------------------------------------------------------------
template<bool FINAL>
__global__ __launch_bounds__(256) void conv3_mfma(
    const ushort* __restrict__ y2F,
    const float* __restrict__ g2, const float* __restrict__ be2,
    const float* __restrict__ W3,
    const float* __restrict__ g3, const float* __restrict__ be3,
    const float* __restrict__ s2S, const float* __restrict__ s2Q,
    float* __restrict__ s3S, float* __restrict__ s3Q,
    const float* __restrict__ grouped, float* __restrict__ outp)
{
    __shared__ float statS[128], statQ[128];   // stats pass
    __shared__ float sc3L[128], sh3L[128];     // final pass
    __shared__ float scoreL[2][64];            // final pass (row-parity buffers)

    const int tid = threadIdx.x;
    const int wid = tid >> 6, l = tid & 63, q = l >> 4, i = l & 15;

    if (!FINAL) {
        if (tid < 128) { statS[tid] = 0.f; statQ[tid] = 0.f; }
    } else if (tid < 128) {
        float m  = s3S[tid] * (1.0f / MTOT);
        float v  = s3Q[tid] * (1.0f / MTOT) - m * m;
        float sc = g3[tid] * rsqrtf(v + BN_EPS);
        sc3L[tid] = sc;
        sh3L[tid] = fmaf(-sc, m, be3[tid]);
    }

    // per-lane bn2 consts for ci = h*32+q*8+j (raw y2 stats; b2 cancels)
    float sc2v[16], sh2v[16];
    #pragma unroll
    for (int h = 0; h < 2; ++h)
      #pragma unroll
      for (int j = 0; j < 8; ++j) {
        int ci = h*32 + q*8 + j;
        float m  = s2S[ci] * (1.0f / MTOT);
        float v  = s2Q[ci] * (1.0f / MTOT) - m * m;
        float sc = g2[ci] * rsqrtf(v + BN_EPS);
        sc2v[h*8+j] = sc;
        sh2v[h*8+j] = fmaf(-sc, m, be2[ci]);
      }
    // A-fragments of W3 (16 frags, registers)
    bf16x8 a3[8][2];
    #pragma unroll
    for (int t = 0; t < 8; ++t)
      #pragma unroll
      for (int h = 0; h < 2; ++h)
        #pragma unroll
        for (int j = 0; j < 8; ++j)
          a3[t][h][j] = (short)f2bf_bits(W3[(t*16 + i)*64 + h*32 + q*8 + j]);

    float ssum[32], ssq[32];
    if (!FINAL) {
        #pragma unroll
        for (int s = 0; s < 32; ++s) { ssum[s] = 0.f; ssq[s] = 0.f; }
    }
    __syncthreads();

    for (int r16 = 0; r16 < 16; ++r16) {
        const int row = blockIdx.x * 16 + r16;
        const ushort* rp = y2F + row*4096 + wid*1024 + q*128 + i*4;
        uint2 u00 = *(const uint2*)(rp);
        uint2 u01 = *(const uint2*)(rp + 64);
        uint2 u10 = *(const uint2*)(rp + 512);
        uint2 u11 = *(const uint2*)(rp + 576);

        bf16x8 xb[2];
        #pragma unroll
        for (int h = 0; h < 2; ++h) {
            u32 w0 = (h == 0) ? u00.x : u10.x;
            u32 w1 = (h == 0) ? u00.y : u10.y;
            u32 w2 = (h == 0) ? u01.x : u11.x;
            u32 w3 = (h == 0) ? u01.y : u11.y;
            float xf[8];
            xf[0] = __uint_as_float(w0 << 16); xf[1] = __uint_as_float(w0 & 0xffff0000u);
            xf[2] = __uint_as_float(w1 << 16); xf[3] = __uint_as_float(w1 & 0xffff0000u);
            xf[4] = __uint_as_float(w2 << 16); xf[5] = __uint_as_float(w2 & 0xffff0000u);
            xf[6] = __uint_as_float(w3 << 16); xf[7] = __uint_as_float(w3 & 0xffff0000u);
            #pragma unroll
            for (int j = 0; j < 8; ++j) {
                float x = fmaxf(fmaf(sc2v[h*8+j], xf[j], sh2v[h*8+j]), 0.f);
                xb[h][j] = (short)f2bf_bits(x);
            }
        }
        f32x4 acc[8];
        #pragma unroll
        for (int t = 0; t < 8; ++t) acc[t] = (f32x4){0.f,0.f,0.f,0.f};
        #pragma unroll
        for (int t = 0; t < 8; ++t) {
            acc[t] = __builtin_amdgcn_mfma_f32_16x16x32_bf16(a3[t][0], xb[0], acc[t], 0, 0, 0);
            acc[t] = __builtin_amdgcn_mfma_f32_16x16x32_bf16(a3[t][1], xb[1], acc[t], 0, 0, 0);
        }

        if (!FINAL) {
            #pragma unroll
            for (int t = 0; t < 8; ++t)
              #pragma unroll
              for (int reg = 0; reg < 4; ++reg) {
                float y = acc[t][reg];
                ssum[t*4+reg] += y;
                ssq[t*4+reg]  = fmaf(y, y, ssq[t*4+reg]);
              }
        } else {
            float mx = -3.4e38f;
            #pragma unroll
            for (int t = 0; t < 8; ++t) {
                float4 s4 = *(const float4*)&sc3L[t*16 + q*4];
                float4 h4 = *(const float4*)&sh3L[t*16 + q*4];
                mx = fmaxf(mx, fmaf(s4.x, acc[t][0], h4.x));
                mx = fmaxf(mx, fmaf(s4.y, acc[t][1], h4.y));
                mx = fmaxf(mx, fmaf(s4.z, acc[t][2], h4.z));
                mx = fmaxf(mx, fmaf(s4.w, acc[t][3], h4.w));
            }
            mx = fmaxf(mx, __shfl_xor(mx, 16, 64));
            mx = fmaxf(mx, __shfl_xor(mx, 32, 64));
            mx = fmaxf(mx, 0.f);                 // relu commutes with max
            if (q == 0) scoreL[r16 & 1][wid*16 + i] = mx;
            __syncthreads();
            if (wid == 0) {
                float sc = scoreL[r16 & 1][l];
                float m2 = sc;
                #pragma unroll
                for (int off = 1; off < 64; off <<= 1) m2 = fmaxf(m2, __shfl_xor(m2, off, 64));
                float e = __expf(sc - m2);
                float se = e;
                #pragma unroll
                for (int off = 1; off < 64; off <<= 1) se += __shfl_xor(se, off, 64);
                float w = e / se;
                const float* gp = grouped + (row*64 + l)*3;
                float ox = w * gp[0], oy = w * gp[1], oz = w * gp[2];
                #pragma unroll
                for (int off = 1; off < 64; off <<= 1) {
                    ox += __shfl_xor(ox, off, 64);
                    oy += __shfl_xor(oy, off, 64);
                    oz += __shfl_xor(oz, off, 64);
                }
                if (l == 0) {
                    int bb = row >> 12, n = row & 4095;
                    outp[bb*3*N_ + 0*N_ + n] = ox;
                    outp[bb*3*N_ + 1*N_ + n] = oy;
                    outp[bb*3*N_ + 2*N_ + n] = oz;
                }
            }
        }
    }

    if (!FINAL) {
        #pragma unroll
        for (int s = 0; s < 32; ++s) {
            #pragma unroll
            for (int off = 1; off < 16; off <<= 1) {
                ssum[s] += __shfl_xor(ssum[s], off, 64);
                ssq[s]  += __shfl_xor(ssq[s],  off, 64);
            }
        }
        if (i == 0) {
            #pragma unroll
            for (int s = 0; s < 32; ++s) {
                int co = (s >> 2)*16 + q*4 + (s & 3);
                atomicAdd(&statS[co], ssum[s]);
                atomicAdd(&statQ[co], ssq[s]);
            }
        }
        __syncthreads();
        if (tid < 128) { atomicAdd(&s3S[tid], statS[tid]); atomicAdd(&s3Q[tid], statQ[tid]); }
    }
}

// ---------------------------------------------------------------------------
extern "C" void kernel_launch(void* const* d_in, const int* in_sizes, int n_in,
                              void* d_out, int out_size, void* d_ws, size_t ws_size,
                              hipStream_t stream)
{
    const float* p1  = (const float*)d_in[0];
    const float* p2  = (const float*)d_in[1];
    // d_in[2] = k (always 32), d_in[3] = t (unused by reference)
    const float* W1  = (const float*)d_in[4];
    const float* b1  = (const float*)d_in[5];
    const float* g1  = (const float*)d_in[6];
    const float* be1 = (const float*)d_in[7];
    const float* W2  = (const float*)d_in[8];
    const float* g2  = (const float*)d_in[10];
    const float* be2 = (const float*)d_in[11];
    const float* W3  = (const float*)d_in[12];
    const float* g3  = (const float*)d_in[14];
    const float* be3 = (const float*)d_in[15];
    // b2 (d_in[9]) and b3 (d_in[13]) cancel through their BatchNorms — unused.

    char* ws = (char*)d_ws;
    const size_t OFF_FEATS   = 4096;
    const size_t OFF_GROUPED = OFF_FEATS + (size_t)MTOT * 4 * 4;        // 16 MB feats
    const size_t OFF_Y2      = OFF_GROUPED + (size_t)MTOT * 3 * 4;      // 12 MB grouped
    const size_t NEEDED      = OFF_Y2 + (size_t)MTOT * 64 * 2;          // 128 MB y2 bf16
    if (ws_size < NEEDED) return;  // fail visibly (wrong output) rather than fault

    float* s1S = (float*)(ws + 0);    float* s1Q = (float*)(ws + 256);
    float* s2S = (float*)(ws + 512);  float* s2Q = (float*)(ws + 768);
    float* s3S = (float*)(ws + 1024); float* s3Q = (float*)(ws + 1536);
    float* feats   = (float*)(ws + OFF_FEATS);
    float* grouped = (float*)(ws + OFF_GROUPED);
    ushort* y2F    = (ushort*)(ws + OFF_Y2);

    hipMemsetAsync(ws, 0, 2048, stream);  // zero all stats accumulators

    knn_kernel<<<512, 256, 0, stream>>>(p1, p2, feats, grouped);
    stats1_kernel<<<1024, 256, 0, stream>>>(feats, W1, b1, s1S, s1Q);
    conv2_mfma<<<1024, 256, 0, stream>>>(feats, W1, b1, g1, be1, W2,
                                         s1S, s1Q, y2F, s2S, s2Q);
    conv3_mfma<false><<<1024, 256, 0, stream>>>(y2F, g2, be2, W3, g3, be3,
                                                s2S, s2Q, s3S, s3Q, nullptr, nullptr);
    conv3_mfma<true><<<1024, 256, 0, stream>>>(y2F, g2, be2, W3, g3, be3,
                                               s2S, s2Q, s3S, s3Q, grouped,
                                               (float*)d_out);
}

// Round 4
// 586.150 us; speedup vs baseline: 3.9651x; 1.5397x over previous
//
#include <hip/hip_runtime.h>
#include <hip/hip_bf16.h>

// Problem constants (fixed by setup_inputs)
#define B_   4
#define N_   4096
#define KNN_ 32
#define KK_  64          // 2*k
#define MTOT 1048576     // B*N*KK
#define BN_EPS 1e-3f

typedef unsigned int u32;
typedef unsigned long long u64;
typedef __attribute__((ext_vector_type(8))) short bf16x8;
typedef __attribute__((ext_vector_type(4))) float f32x4;

__device__ __forceinline__ ushort f2bf_bits(float f) {   // RNE, finite inputs only
    u32 b = __float_as_uint(f);
    b += 0x7fffu + ((b >> 16) & 1u);
    return (ushort)(b >> 16);
}

// ---------------------------------------------------------------------------
// K1: dual KNN, atomic-free. One wave per query row.
// Keys computed once into 64 VGPRs; per-lane sorted kept-4; threshold via
// ballot-popcount integer bisection over kept-4 union (certified exact
// against full keys, rare fallback bisection); ballot-prefix emission.
// grid: 512 blocks = 2 pairs * 4 batches * 64 row-chunks; 16 rows/wave.
// ---------------------------------------------------------------------------
__global__ __launch_bounds__(256, 2) void knn_kernel(
    const float* __restrict__ p1, const float* __restrict__ p2,
    float* __restrict__ feats, float* __restrict__ grouped)
{
    __shared__ float4 cand[N_];                  // 64 KB: x, y, z, |c|^2

    const int tid  = threadIdx.x;
    const int wave = tid >> 6, lane = tid & 63;
    const int pb   = blockIdx.x >> 6;            // 0..7
    const int pr   = pb >> 2, b = pb & 3;
    const int nbase = (blockIdx.x & 63) * 64;

    const float* srcb = (pr ? p2 : p1) + (size_t)b * 3 * N_;
    for (int n = tid; n < N_; n += 256) {
        float x = srcb[n], y = srcb[N_ + n], z = srcb[2*N_ + n];
        cand[n] = make_float4(x, y, z, fmaf(x, x, fmaf(y, y, z*z)));
    }
    __syncthreads();

    const float* p1b = p1 + (size_t)b * 3 * N_;
    const u64 below = (1ull << lane) - 1ull;

    for (int r = 0; r < 16; ++r) {
        const int n = nbase + wave * 16 + r;
        float qx, qy, qz;
        if (pr == 0) { float4 q = cand[n]; qx = q.x; qy = q.y; qz = q.z; }
        else         { qx = p1b[n]; qy = p1b[N_ + n]; qz = p1b[2*N_ + n]; }
        const float s1 = fmaf(qx, qx, fmaf(qy, qy, qz*qz));

        // ---- phase A: keys (once, registers) + sorted kept-4 ----
        u32 keys[64];
        u32 k0 = 0xFFFFFFFFu, k1 = 0xFFFFFFFFu, k2 = 0xFFFFFFFFu, k3 = 0xFFFFFFFFu;
        #pragma unroll
        for (int j = 0; j < 64; ++j) {
            float4 c = cand[j * 64 + lane];
            float dot = fmaf(qx, c.x, fmaf(qy, c.y, qz * c.z));
            float d2  = fmaf(-2.0f, dot, s1 + c.w);
            u32 u = __float_as_uint(d2);
            u32 key = u ^ (u32)(((int)u >> 31) | 0x80000000);
            keys[j] = key;
            k3 = min(k3, key);
            u32 t;
            t = min(k2, k3); k3 = max(k2, k3); k2 = t;
            t = min(k1, k2); k2 = max(k1, k2); k1 = t;
            t = min(k0, k1); k1 = max(k0, k1); k0 = t;
        }

        // ---- phase B: bisect rank-31 threshold over kept-4 union ----
        u32 lo = 0u, hi = 0xFFFFFFFFu;
        while (lo < hi) {
            u32 mid = lo + ((hi - lo) >> 1);
            int c = __popcll(__ballot(k0 <= mid)) + __popcll(__ballot(k1 <= mid))
                  + __popcll(__ballot(k2 <= mid)) + __popcll(__ballot(k3 <= mid));
            if (c >= 32) hi = mid; else lo = mid + 1;
        }
        u32 T = lo;

        // ---- phase C: certify against full key set (exact count) ----
        int nl = 0;
        #pragma unroll
        for (int j = 0; j < 64; ++j) nl += __popcll(__ballot(keys[j] < T));
        if (nl > 31) {                      // kept-4 truncated the true top-32 (rare)
            lo = 0u; hi = T;
            while (lo < hi) {
                u32 mid = lo + ((hi - lo) >> 1);
                int c = 0;
                #pragma unroll
                for (int j = 0; j < 64; ++j) c += __popcll(__ballot(keys[j] <= mid));
                if (c >= 32) hi = mid; else lo = mid + 1;
            }
            T = lo;
            nl = 0;
            #pragma unroll
            for (int j = 0; j < 64; ++j) nl += __popcll(__ballot(keys[j] < T));
        }
        const int need_eq = 32 - nl;        // >= 1; ties resolved by candidate index

        // ---- phase D: emission via ballot prefix (no atomics) ----
        float* fout = feats   + ((size_t)(b * N_ + n) * KK_ + pr * KNN_) * 4;
        float* gout = grouped + ((size_t)(b * N_ + n) * KK_ + pr * KNN_) * 3;
        int base = 0, eq_seen = 0;
        #pragma unroll
        for (int j = 0; j < 64; ++j) {
            u32 key = keys[j];
            bool lt = key < T;
            bool eq = key == T;
            u64 mlt = __ballot(lt);
            u64 meq = __ballot(eq);
            if (mlt | meq) {
                int slot = -1;
                if (lt) slot = base + __popcll(mlt & below);
                else if (eq) {
                    int es = eq_seen + __popcll(meq & below);
                    if (es < need_eq) slot = nl + es;
                }
                if (slot >= 0) {
                    float4 cd = cand[j * 64 + lane];
                    float rx = cd.x - qx, ry = cd.y - qy, rz = cd.z - qz;
                    float dist = sqrtf(fmaf(rx, rx, fmaf(ry, ry, rz*rz)));
                    *(float4*)(fout + slot * 4) = make_float4(rx, ry, rz, dist);
                    gout[slot*3 + 0] = cd.x; gout[slot*3 + 1] = cd.y; gout[slot*3 + 2] = cd.z;
                }
                base    += __popcll(mlt);
                eq_seen += __popcll(meq);
            }
        }
    }
}

// ---------------------------------------------------------------------------
// K2: stats of y1 = W1@feat + b1 (per-channel sum / sumsq over 1M positions)
// ---------------------------------------------------------------------------
__global__ __launch_bounds__(256) void stats1_kernel(
    const float* __restrict__ feats,
    const float* __restrict__ W1, const float* __restrict__ b1,
    float* __restrict__ s1S, float* __restrict__ s1Q)
{
    __shared__ float4 featL[256];
    __shared__ float red[512];
    const int tid = threadIdx.x;
    const int ch = tid & 63, pg = tid >> 6;
    float w0 = W1[ch*4+0], w1v = W1[ch*4+1];
    float w2v = W1[ch*4+2], w3v = W1[ch*4+3];
    float bb = b1[ch];
    float sum = 0.f, sq = 0.f;
    for (int chunk = 0; chunk < 4; ++chunk) {
        __syncthreads();
        size_t pbase = (size_t)blockIdx.x * 1024 + (size_t)chunk * 256;
        featL[tid] = ((const float4*)feats)[pbase + tid];
        __syncthreads();
        for (int i = 0; i < 64; ++i) {
            float4 f = featL[pg * 64 + i];
            float y = bb + w0*f.x + w1v*f.y + w2v*f.z + w3v*f.w;
            sum += y; sq += y * y;
        }
    }
    red[tid] = sum; red[256 + tid] = sq;
    __syncthreads();
    if (tid < 64) {
        float s = red[tid] + red[64+tid] + red[128+tid] + red[192+tid];
        float q = red[256+tid] + red[320+tid] + red[384+tid] + red[448+tid];
        atomicAdd(&s1S[tid], s);
        atomicAdd(&s1Q[tid], q);
    }
}

// ---------------------------------------------------------------------------
// K3: MFMA conv2 (unchanged from round 3)
// ---------------------------------------------------------------------------
__global__ __launch_bounds__(256) void conv2_mfma(
    const float* __restrict__ feats,
    const float* __restrict__ W1, const float* __restrict__ b1,
    const float* __restrict__ g1, const float* __restrict__ be1,
    const float* __restrict__ W2,
    const float* __restrict__ s1S, const float* __restrict__ s1Q,
    ushort* __restrict__ y2F, float* __restrict__ s2S, float* __restrict__ s2Q)
{
    __shared__ float statS[64], statQ[64];
    const int tid = threadIdx.x;
    const int wid = tid >> 6, l = tid & 63, q = l >> 4, i = l & 15;
    if (tid < 64) { statS[tid] = 0.f; statQ[tid] = 0.f; }

    float4 w1f[16];
    float  c1v[16];
    #pragma unroll
    for (int h = 0; h < 2; ++h)
      #pragma unroll
      for (int j = 0; j < 8; ++j) {
        int ci = h*32 + q*8 + j;
        float m  = s1S[ci] * (1.0f / MTOT);
        float v  = s1Q[ci] * (1.0f / MTOT) - m * m;
        float sc = g1[ci] * rsqrtf(v + BN_EPS);
        w1f[h*8+j] = make_float4(sc*W1[ci*4+0], sc*W1[ci*4+1], sc*W1[ci*4+2], sc*W1[ci*4+3]);
        c1v[h*8+j] = fmaf(sc, b1[ci] - m, be1[ci]);
      }
    bf16x8 a2[4][2];
    #pragma unroll
    for (int t = 0; t < 4; ++t)
      #pragma unroll
      for (int h = 0; h < 2; ++h)
        #pragma unroll
        for (int j = 0; j < 8; ++j)
          a2[t][h][j] = (short)f2bf_bits(W2[(t*16 + i)*64 + h*32 + q*8 + j]);

    float ssum[16], ssq[16];
    #pragma unroll
    for (int s = 0; s < 16; ++s) { ssum[s] = 0.f; ssq[s] = 0.f; }
    __syncthreads();

    for (int r16 = 0; r16 < 16; ++r16) {
        const int row = blockIdx.x * 16 + r16;
        float4 f = ((const float4*)feats)[row*64 + wid*16 + i];
        bf16x8 xb[2];
        #pragma unroll
        for (int h = 0; h < 2; ++h)
          #pragma unroll
          for (int j = 0; j < 8; ++j) {
            float4 w = w1f[h*8+j];
            float x = fmaxf(fmaf(w.x, f.x, fmaf(w.y, f.y, fmaf(w.z, f.z, fmaf(w.w, f.w, c1v[h*8+j])))), 0.f);
            xb[h][j] = (short)f2bf_bits(x);
          }
        f32x4 acc[4];
        #pragma unroll
        for (int t = 0; t < 4; ++t) acc[t] = (f32x4){0.f,0.f,0.f,0.f};
        #pragma unroll
        for (int t = 0; t < 4; ++t) {
            acc[t] = __builtin_amdgcn_mfma_f32_16x16x32_bf16(a2[t][0], xb[0], acc[t], 0, 0, 0);
            acc[t] = __builtin_amdgcn_mfma_f32_16x16x32_bf16(a2[t][1], xb[1], acc[t], 0, 0, 0);
        }
        ushort* wp = y2F + row*4096 + wid*1024 + q*64 + i*4;
        #pragma unroll
        for (int t = 0; t < 4; ++t) {
            #pragma unroll
            for (int reg = 0; reg < 4; ++reg) {
                float y = acc[t][reg];
                ssum[t*4+reg] += y;
                ssq[t*4+reg]  = fmaf(y, y, ssq[t*4+reg]);
            }
            uint2 pk;
            pk.x = (u32)f2bf_bits(acc[t][0]) | ((u32)f2bf_bits(acc[t][1]) << 16);
            pk.y = (u32)f2bf_bits(acc[t][2]) | ((u32)f2bf_bits(acc[t][3]) << 16);
            *(uint2*)(wp + t*256) = pk;
        }
    }
    #pragma unroll
    for (int s = 0; s < 16; ++s) {
        #pragma unroll
        for (int off = 1; off < 16; off <<= 1) {
            ssum[s] += __shfl_xor(ssum[s], off, 64);
            ssq[s]  += __shfl_xor(ssq[s],  off, 64);
        }
    }
    if (i == 0) {
        #pragma unroll
        for (int s = 0; s < 16; ++s) {
            int co = (s >> 2)*16 + q*4 + (s & 3);
            atomicAdd(&statS[co], ssum[s]);
            atomicAdd(&statQ[co], ssq[s]);
        }
    }
    __syncthreads();
    if (tid < 64) { atomicAdd(&s2S[tid], statS[tid]); atomicAdd(&s2Q[tid], statQ[tid]); }
}

// ---------------------------------------------------------------------------
// K4/K5: MFMA conv3 (unchanged from round 3)
// ---------------------------------------------------------------------------
template<bool FINAL>
__global__ __launch_bounds__(256) void conv3_mfma(
    const ushort* __restrict__ y2F,
    const float* __restrict__ g2, const float* __restrict__ be2,
    const float* __restrict__ W3,
    const float* __restrict__ g3, const float* __restrict__ be3,
    const float* __restrict__ s2S, const float* __restrict__ s2Q,
    float* __restrict__ s3S, float* __restrict__ s3Q,
    const float* __restrict__ grouped, float* __restrict__ outp)
{
    __shared__ float statS[128], statQ[128];
    __shared__ float sc3L[128], sh3L[128];
    __shared__ float scoreL[2][64];

    const int tid = threadIdx.x;
    const int wid = tid >> 6, l = tid & 63, q = l >> 4, i = l & 15;

    if (!FINAL) {
        if (tid < 128) { statS[tid] = 0.f; statQ[tid] = 0.f; }
    } else if (tid < 128) {
        float m  = s3S[tid] * (1.0f / MTOT);
        float v  = s3Q[tid] * (1.0f / MTOT) - m * m;
        float sc = g3[tid] * rsqrtf(v + BN_EPS);
        sc3L[tid] = sc;
        sh3L[tid] = fmaf(-sc, m, be3[tid]);
    }

    float sc2v[16], sh2v[16];
    #pragma unroll
    for (int h = 0; h < 2; ++h)
      #pragma unroll
      for (int j = 0; j < 8; ++j) {
        int ci = h*32 + q*8 + j;
        float m  = s2S[ci] * (1.0f / MTOT);
        float v  = s2Q[ci] * (1.0f / MTOT) - m * m;
        float sc = g2[ci] * rsqrtf(v + BN_EPS);
        sc2v[h*8+j] = sc;
        sh2v[h*8+j] = fmaf(-sc, m, be2[ci]);
      }
    bf16x8 a3[8][2];
    #pragma unroll
    for (int t = 0; t < 8; ++t)
      #pragma unroll
      for (int h = 0; h < 2; ++h)
        #pragma unroll
        for (int j = 0; j < 8; ++j)
          a3[t][h][j] = (short)f2bf_bits(W3[(t*16 + i)*64 + h*32 + q*8 + j]);

    float ssum[32], ssq[32];
    if (!FINAL) {
        #pragma unroll
        for (int s = 0; s < 32; ++s) { ssum[s] = 0.f; ssq[s] = 0.f; }
    }
    __syncthreads();

    for (int r16 = 0; r16 < 16; ++r16) {
        const int row = blockIdx.x * 16 + r16;
        const ushort* rp = y2F + row*4096 + wid*1024 + q*128 + i*4;
        uint2 u00 = *(const uint2*)(rp);
        uint2 u01 = *(const uint2*)(rp + 64);
        uint2 u10 = *(const uint2*)(rp + 512);
        uint2 u11 = *(const uint2*)(rp + 576);

        bf16x8 xb[2];
        #pragma unroll
        for (int h = 0; h < 2; ++h) {
            u32 w0 = (h == 0) ? u00.x : u10.x;
            u32 w1 = (h == 0) ? u00.y : u10.y;
            u32 w2 = (h == 0) ? u01.x : u11.x;
            u32 w3 = (h == 0) ? u01.y : u11.y;
            float xf[8];
            xf[0] = __uint_as_float(w0 << 16); xf[1] = __uint_as_float(w0 & 0xffff0000u);
            xf[2] = __uint_as_float(w1 << 16); xf[3] = __uint_as_float(w1 & 0xffff0000u);
            xf[4] = __uint_as_float(w2 << 16); xf[5] = __uint_as_float(w2 & 0xffff0000u);
            xf[6] = __uint_as_float(w3 << 16); xf[7] = __uint_as_float(w3 & 0xffff0000u);
            #pragma unroll
            for (int j = 0; j < 8; ++j) {
                float x = fmaxf(fmaf(sc2v[h*8+j], xf[j], sh2v[h*8+j]), 0.f);
                xb[h][j] = (short)f2bf_bits(x);
            }
        }
        f32x4 acc[8];
        #pragma unroll
        for (int t = 0; t < 8; ++t) acc[t] = (f32x4){0.f,0.f,0.f,0.f};
        #pragma unroll
        for (int t = 0; t < 8; ++t) {
            acc[t] = __builtin_amdgcn_mfma_f32_16x16x32_bf16(a3[t][0], xb[0], acc[t], 0, 0, 0);
            acc[t] = __builtin_amdgcn_mfma_f32_16x16x32_bf16(a3[t][1], xb[1], acc[t], 0, 0, 0);
        }

        if (!FINAL) {
            #pragma unroll
            for (int t = 0; t < 8; ++t)
              #pragma unroll
              for (int reg = 0; reg < 4; ++reg) {
                float y = acc[t][reg];
                ssum[t*4+reg] += y;
                ssq[t*4+reg]  = fmaf(y, y, ssq[t*4+reg]);
              }
        } else {
            float mx = -3.4e38f;
            #pragma unroll
            for (int t = 0; t < 8; ++t) {
                float4 s4 = *(const float4*)&sc3L[t*16 + q*4];
                float4 h4 = *(const float4*)&sh3L[t*16 + q*4];
                mx = fmaxf(mx, fmaf(s4.x, acc[t][0], h4.x));
                mx = fmaxf(mx, fmaf(s4.y, acc[t][1], h4.y));
                mx = fmaxf(mx, fmaf(s4.z, acc[t][2], h4.z));
                mx = fmaxf(mx, fmaf(s4.w, acc[t][3], h4.w));
            }
            mx = fmaxf(mx, __shfl_xor(mx, 16, 64));
            mx = fmaxf(mx, __shfl_xor(mx, 32, 64));
            mx = fmaxf(mx, 0.f);
            if (q == 0) scoreL[r16 & 1][wid*16 + i] = mx;
            __syncthreads();
            if (wid == 0) {
                float sc = scoreL[r16 & 1][l];
                float m2 = sc;
                #pragma unroll
                for (int off = 1; off < 64; off <<= 1) m2 = fmaxf(m2, __shfl_xor(m2, off, 64));
                float e = __expf(sc - m2);
                float se = e;
                #pragma unroll
                for (int off = 1; off < 64; off <<= 1) se += __shfl_xor(se, off, 64);
                float w = e / se;
                const float* gp = grouped + (row*64 + l)*3;
                float ox = w * gp[0], oy = w * gp[1], oz = w * gp[2];
                #pragma unroll
                for (int off = 1; off < 64; off <<= 1) {
                    ox += __shfl_xor(ox, off, 64);
                    oy += __shfl_xor(oy, off, 64);
                    oz += __shfl_xor(oz, off, 64);
                }
                if (l == 0) {
                    int bb = row >> 12, n = row & 4095;
                    outp[bb*3*N_ + 0*N_ + n] = ox;
                    outp[bb*3*N_ + 1*N_ + n] = oy;
                    outp[bb*3*N_ + 2*N_ + n] = oz;
                }
            }
        }
    }

    if (!FINAL) {
        #pragma unroll
        for (int s = 0; s < 32; ++s) {
            #pragma unroll
            for (int off = 1; off < 16; off <<= 1) {
                ssum[s] += __shfl_xor(ssum[s], off, 64);
                ssq[s]  += __shfl_xor(ssq[s],  off, 64);
            }
        }
        if (i == 0) {
            #pragma unroll
            for (int s = 0; s < 32; ++s) {
                int co = (s >> 2)*16 + q*4 + (s & 3);
                atomicAdd(&statS[co], ssum[s]);
                atomicAdd(&statQ[co], ssq[s]);
            }
        }
        __syncthreads();
        if (tid < 128) { atomicAdd(&s3S[tid], statS[tid]); atomicAdd(&s3Q[tid], statQ[tid]); }
    }
}

// ---------------------------------------------------------------------------
extern "C" void kernel_launch(void* const* d_in, const int* in_sizes, int n_in,
                              void* d_out, int out_size, void* d_ws, size_t ws_size,
                              hipStream_t stream)
{
    const float* p1  = (const float*)d_in[0];
    const float* p2  = (const float*)d_in[1];
    // d_in[2] = k (always 32), d_in[3] = t (unused by reference)
    const float* W1  = (const float*)d_in[4];
    const float* b1  = (const float*)d_in[5];
    const float* g1  = (const float*)d_in[6];
    const float* be1 = (const float*)d_in[7];
    const float* W2  = (const float*)d_in[8];
    const float* g2  = (const float*)d_in[10];
    const float* be2 = (const float*)d_in[11];
    const float* W3  = (const float*)d_in[12];
    const float* g3  = (const float*)d_in[14];
    const float* be3 = (const float*)d_in[15];
    // b2 (d_in[9]) and b3 (d_in[13]) cancel through their BatchNorms — unused.

    char* ws = (char*)d_ws;
    const size_t OFF_FEATS   = 4096;
    const size_t OFF_GROUPED = OFF_FEATS + (size_t)MTOT * 4 * 4;        // 16 MB feats
    const size_t OFF_Y2      = OFF_GROUPED + (size_t)MTOT * 3 * 4;      // 12 MB grouped
    const size_t NEEDED      = OFF_Y2 + (size_t)MTOT * 64 * 2;          // 128 MB y2 bf16
    if (ws_size < NEEDED) return;  // fail visibly (wrong output) rather than fault

    float* s1S = (float*)(ws + 0);    float* s1Q = (float*)(ws + 256);
    float* s2S = (float*)(ws + 512);  float* s2Q = (float*)(ws + 768);
    float* s3S = (float*)(ws + 1024); float* s3Q = (float*)(ws + 1536);
    float* feats   = (float*)(ws + OFF_FEATS);
    float* grouped = (float*)(ws + OFF_GROUPED);
    ushort* y2F    = (ushort*)(ws + OFF_Y2);

    hipMemsetAsync(ws, 0, 2048, stream);  // zero all stats accumulators

    knn_kernel<<<512, 256, 0, stream>>>(p1, p2, feats, grouped);
    stats1_kernel<<<1024, 256, 0, stream>>>(feats, W1, b1, s1S, s1Q);
    conv2_mfma<<<1024, 256, 0, stream>>>(feats, W1, b1, g1, be1, W2,
                                         s1S, s1Q, y2F, s2S, s2Q);
    conv3_mfma<false><<<1024, 256, 0, stream>>>(y2F, g2, be2, W3, g3, be3,
                                                s2S, s2Q, s3S, s3Q, nullptr, nullptr);
    conv3_mfma<true><<<1024, 256, 0, stream>>>(y2F, g2, be2, W3, g3, be3,
                                               s2S, s2Q, s3S, s3Q, grouped,
                                               (float*)d_out);
}

// Round 5
// 567.340 us; speedup vs baseline: 4.0965x; 1.0332x over previous
//
#include <hip/hip_runtime.h>
#include <hip/hip_bf16.h>

// Problem constants (fixed by setup_inputs)
#define B_   4
#define N_   4096
#define KNN_ 32
#define KK_  64          // 2*k
#define MTOT 1048576     // B*N*KK
#define BN_EPS 1e-3f

typedef unsigned int u32;
typedef unsigned long long u64;
typedef __attribute__((ext_vector_type(8))) short bf16x8;
typedef __attribute__((ext_vector_type(4))) float f32x4;

__device__ __forceinline__ ushort f2bf_bits(float f) {   // RNE, finite inputs only
    u32 b = __float_as_uint(f);
    b += 0x7fffu + ((b >> 16) & 1u);
    return (ushort)(b >> 16);
}

// ---------------------------------------------------------------------------
// K1: dual KNN, atomic-free. One wave per query row.
// 48 KB LDS (xy-plane + z-plane) -> 3 blocks/CU; grid 1024 so 3 are resident.
// Keys computed once into 64 VGPRs (bit-identical fmaf chain vs round 4);
// per-lane sorted kept-4; threshold via ballot-popcount bisection (certified
// exact, rare fallback); ballot-prefix emission.
// grid: 1024 blocks = 2 pairs * 4 batches * 128 row-chunks; 8 rows/wave.
// ---------------------------------------------------------------------------
__global__ __launch_bounds__(256, 3) void knn_kernel(
    const float* __restrict__ p1, const float* __restrict__ p2,
    float* __restrict__ feats, float* __restrict__ grouped)
{
    __shared__ float2 cxy[N_];                   // 32 KB
    __shared__ float  cz[N_];                    // 16 KB

    const int tid  = threadIdx.x;
    const int wave = tid >> 6, lane = tid & 63;
    const int pb   = blockIdx.x >> 7;            // 0..7
    const int pr   = pb >> 2, b = pb & 3;
    const int nbase = (blockIdx.x & 127) * 32;

    const float* srcb = (pr ? p2 : p1) + (size_t)b * 3 * N_;
    for (int n = tid; n < N_; n += 256) {
        float x = srcb[n], y = srcb[N_ + n], z = srcb[2*N_ + n];
        cxy[n] = make_float2(x, y);
        cz[n]  = z;
    }
    __syncthreads();

    const float* p1b = p1 + (size_t)b * 3 * N_;
    const u64 below = (1ull << lane) - 1ull;

    for (int r = 0; r < 8; ++r) {
        const int n = nbase + wave * 8 + r;
        float qx, qy, qz;
        if (pr == 0) { float2 q = cxy[n]; qx = q.x; qy = q.y; qz = cz[n]; }
        else         { qx = p1b[n]; qy = p1b[N_ + n]; qz = p1b[2*N_ + n]; }
        const float s1 = fmaf(qx, qx, fmaf(qy, qy, qz*qz));

        // ---- phase A: keys (once, registers) + sorted kept-4 ----
        u32 keys[64];
        u32 k0 = 0xFFFFFFFFu, k1 = 0xFFFFFFFFu, k2 = 0xFFFFFFFFu, k3 = 0xFFFFFFFFu;
        #pragma unroll
        for (int j = 0; j < 64; ++j) {
            float2 cx2 = cxy[j * 64 + lane];
            float  cz1 = cz[j * 64 + lane];
            // |c|^2 with the same fmaf chain as staging used before — keys
            // are bit-identical to rounds 3/4.
            float cw  = fmaf(cx2.x, cx2.x, fmaf(cx2.y, cx2.y, cz1*cz1));
            float dot = fmaf(qx, cx2.x, fmaf(qy, cx2.y, qz * cz1));
            float d2  = fmaf(-2.0f, dot, s1 + cw);
            u32 u = __float_as_uint(d2);
            u32 key = u ^ (u32)(((int)u >> 31) | 0x80000000);
            keys[j] = key;
            k3 = min(k3, key);
            u32 t;
            t = min(k2, k3); k3 = max(k2, k3); k2 = t;
            t = min(k1, k2); k2 = max(k1, k2); k1 = t;
            t = min(k0, k1); k1 = max(k0, k1); k0 = t;
        }

        // ---- phase B: bisect rank-31 threshold over kept-4 union ----
        u32 lo = 0u, hi = 0xFFFFFFFFu;
        while (lo < hi) {
            u32 mid = lo + ((hi - lo) >> 1);
            int c = __popcll(__ballot(k0 <= mid)) + __popcll(__ballot(k1 <= mid))
                  + __popcll(__ballot(k2 <= mid)) + __popcll(__ballot(k3 <= mid));
            if (c >= 32) hi = mid; else lo = mid + 1;
        }
        u32 T = lo;

        // ---- phase C: certify against full key set (exact count) ----
        int nl = 0;
        #pragma unroll
        for (int j = 0; j < 64; ++j) nl += __popcll(__ballot(keys[j] < T));
        if (nl > 31) {                      // kept-4 truncated the true top-32 (rare)
            lo = 0u; hi = T;
            while (lo < hi) {
                u32 mid = lo + ((hi - lo) >> 1);
                int c = 0;
                #pragma unroll
                for (int j = 0; j < 64; ++j) c += __popcll(__ballot(keys[j] <= mid));
                if (c >= 32) hi = mid; else lo = mid + 1;
            }
            T = lo;
            nl = 0;
            #pragma unroll
            for (int j = 0; j < 64; ++j) nl += __popcll(__ballot(keys[j] < T));
        }
        const int need_eq = 32 - nl;        // >= 1; ties resolved by candidate index

        // ---- phase D: emission via ballot prefix (no atomics) ----
        float* fout = feats   + ((size_t)(b * N_ + n) * KK_ + pr * KNN_) * 4;
        float* gout = grouped + ((size_t)(b * N_ + n) * KK_ + pr * KNN_) * 3;
        int base = 0, eq_seen = 0;
        #pragma unroll
        for (int j = 0; j < 64; ++j) {
            u32 key = keys[j];
            bool lt = key < T;
            bool eq = key == T;
            u64 mlt = __ballot(lt);
            u64 meq = __ballot(eq);
            if (mlt | meq) {
                int slot = -1;
                if (lt) slot = base + __popcll(mlt & below);
                else if (eq) {
                    int es = eq_seen + __popcll(meq & below);
                    if (es < need_eq) slot = nl + es;
                }
                if (slot >= 0) {
                    float2 cx2 = cxy[j * 64 + lane];
                    float  cz1 = cz[j * 64 + lane];
                    float rx = cx2.x - qx, ry = cx2.y - qy, rz = cz1 - qz;
                    float dist = sqrtf(fmaf(rx, rx, fmaf(ry, ry, rz*rz)));
                    *(float4*)(fout + slot * 4) = make_float4(rx, ry, rz, dist);
                    gout[slot*3 + 0] = cx2.x; gout[slot*3 + 1] = cx2.y; gout[slot*3 + 2] = cz1;
                }
                base    += __popcll(mlt);
                eq_seen += __popcll(meq);
            }
        }
    }
}

// ---------------------------------------------------------------------------
// K2: stats of y1 = W1@feat + b1 (per-channel sum / sumsq over 1M positions)
// ---------------------------------------------------------------------------
__global__ __launch_bounds__(256) void stats1_kernel(
    const float* __restrict__ feats,
    const float* __restrict__ W1, const float* __restrict__ b1,
    float* __restrict__ s1S, float* __restrict__ s1Q)
{
    __shared__ float4 featL[256];
    __shared__ float red[512];
    const int tid = threadIdx.x;
    const int ch = tid & 63, pg = tid >> 6;
    float w0 = W1[ch*4+0], w1v = W1[ch*4+1];
    float w2v = W1[ch*4+2], w3v = W1[ch*4+3];
    float bb = b1[ch];
    float sum = 0.f, sq = 0.f;
    for (int chunk = 0; chunk < 4; ++chunk) {
        __syncthreads();
        size_t pbase = (size_t)blockIdx.x * 1024 + (size_t)chunk * 256;
        featL[tid] = ((const float4*)feats)[pbase + tid];
        __syncthreads();
        for (int i = 0; i < 64; ++i) {
            float4 f = featL[pg * 64 + i];
            float y = bb + w0*f.x + w1v*f.y + w2v*f.z + w3v*f.w;
            sum += y; sq += y * y;
        }
    }
    red[tid] = sum; red[256 + tid] = sq;
    __syncthreads();
    if (tid < 64) {
        float s = red[tid] + red[64+tid] + red[128+tid] + red[192+tid];
        float q = red[256+tid] + red[320+tid] + red[384+tid] + red[448+tid];
        atomicAdd(&s1S[tid], s);
        atomicAdd(&s1Q[tid], q);
    }
}

// ---------------------------------------------------------------------------
// K3: MFMA conv2 (unchanged)
// ---------------------------------------------------------------------------
__global__ __launch_bounds__(256) void conv2_mfma(
    const float* __restrict__ feats,
    const float* __restrict__ W1, const float* __restrict__ b1,
    const float* __restrict__ g1, const float* __restrict__ be1,
    const float* __restrict__ W2,
    const float* __restrict__ s1S, const float* __restrict__ s1Q,
    ushort* __restrict__ y2F, float* __restrict__ s2S, float* __restrict__ s2Q)
{
    __shared__ float statS[64], statQ[64];
    const int tid = threadIdx.x;
    const int wid = tid >> 6, l = tid & 63, q = l >> 4, i = l & 15;
    if (tid < 64) { statS[tid] = 0.f; statQ[tid] = 0.f; }

    float4 w1f[16];
    float  c1v[16];
    #pragma unroll
    for (int h = 0; h < 2; ++h)
      #pragma unroll
      for (int j = 0; j < 8; ++j) {
        int ci = h*32 + q*8 + j;
        float m  = s1S[ci] * (1.0f / MTOT);
        float v  = s1Q[ci] * (1.0f / MTOT) - m * m;
        float sc = g1[ci] * rsqrtf(v + BN_EPS);
        w1f[h*8+j] = make_float4(sc*W1[ci*4+0], sc*W1[ci*4+1], sc*W1[ci*4+2], sc*W1[ci*4+3]);
        c1v[h*8+j] = fmaf(sc, b1[ci] - m, be1[ci]);
      }
    bf16x8 a2[4][2];
    #pragma unroll
    for (int t = 0; t < 4; ++t)
      #pragma unroll
      for (int h = 0; h < 2; ++h)
        #pragma unroll
        for (int j = 0; j < 8; ++j)
          a2[t][h][j] = (short)f2bf_bits(W2[(t*16 + i)*64 + h*32 + q*8 + j]);

    float ssum[16], ssq[16];
    #pragma unroll
    for (int s = 0; s < 16; ++s) { ssum[s] = 0.f; ssq[s] = 0.f; }
    __syncthreads();

    for (int r16 = 0; r16 < 16; ++r16) {
        const int row = blockIdx.x * 16 + r16;
        float4 f = ((const float4*)feats)[row*64 + wid*16 + i];
        bf16x8 xb[2];
        #pragma unroll
        for (int h = 0; h < 2; ++h)
          #pragma unroll
          for (int j = 0; j < 8; ++j) {
            float4 w = w1f[h*8+j];
            float x = fmaxf(fmaf(w.x, f.x, fmaf(w.y, f.y, fmaf(w.z, f.z, fmaf(w.w, f.w, c1v[h*8+j])))), 0.f);
            xb[h][j] = (short)f2bf_bits(x);
          }
        f32x4 acc[4];
        #pragma unroll
        for (int t = 0; t < 4; ++t) acc[t] = (f32x4){0.f,0.f,0.f,0.f};
        #pragma unroll
        for (int t = 0; t < 4; ++t) {
            acc[t] = __builtin_amdgcn_mfma_f32_16x16x32_bf16(a2[t][0], xb[0], acc[t], 0, 0, 0);
            acc[t] = __builtin_amdgcn_mfma_f32_16x16x32_bf16(a2[t][1], xb[1], acc[t], 0, 0, 0);
        }
        ushort* wp = y2F + row*4096 + wid*1024 + q*64 + i*4;
        #pragma unroll
        for (int t = 0; t < 4; ++t) {
            #pragma unroll
            for (int reg = 0; reg < 4; ++reg) {
                float y = acc[t][reg];
                ssum[t*4+reg] += y;
                ssq[t*4+reg]  = fmaf(y, y, ssq[t*4+reg]);
            }
            uint2 pk;
            pk.x = (u32)f2bf_bits(acc[t][0]) | ((u32)f2bf_bits(acc[t][1]) << 16);
            pk.y = (u32)f2bf_bits(acc[t][2]) | ((u32)f2bf_bits(acc[t][3]) << 16);
            *(uint2*)(wp + t*256) = pk;
        }
    }
    #pragma unroll
    for (int s = 0; s < 16; ++s) {
        #pragma unroll
        for (int off = 1; off < 16; off <<= 1) {
            ssum[s] += __shfl_xor(ssum[s], off, 64);
            ssq[s]  += __shfl_xor(ssq[s],  off, 64);
        }
    }
    if (i == 0) {
        #pragma unroll
        for (int s = 0; s < 16; ++s) {
            int co = (s >> 2)*16 + q*4 + (s & 3);
            atomicAdd(&statS[co], ssum[s]);
            atomicAdd(&statQ[co], ssq[s]);
        }
    }
    __syncthreads();
    if (tid < 64) { atomicAdd(&s2S[tid], statS[tid]); atomicAdd(&s2Q[tid], statQ[tid]); }
}

// ---------------------------------------------------------------------------
// K4/K5: MFMA conv3 (unchanged)
// ---------------------------------------------------------------------------
template<bool FINAL>
__global__ __launch_bounds__(256) void conv3_mfma(
    const ushort* __restrict__ y2F,
    const float* __restrict__ g2, const float* __restrict__ be2,
    const float* __restrict__ W3,
    const float* __restrict__ g3, const float* __restrict__ be3,
    const float* __restrict__ s2S, const float* __restrict__ s2Q,
    float* __restrict__ s3S, float* __restrict__ s3Q,
    const float* __restrict__ grouped, float* __restrict__ outp)
{
    __shared__ float statS[128], statQ[128];
    __shared__ float sc3L[128], sh3L[128];
    __shared__ float scoreL[2][64];

    const int tid = threadIdx.x;
    const int wid = tid >> 6, l = tid & 63, q = l >> 4, i = l & 15;

    if (!FINAL) {
        if (tid < 128) { statS[tid] = 0.f; statQ[tid] = 0.f; }
    } else if (tid < 128) {
        float m  = s3S[tid] * (1.0f / MTOT);
        float v  = s3Q[tid] * (1.0f / MTOT) - m * m;
        float sc = g3[tid] * rsqrtf(v + BN_EPS);
        sc3L[tid] = sc;
        sh3L[tid] = fmaf(-sc, m, be3[tid]);
    }

    float sc2v[16], sh2v[16];
    #pragma unroll
    for (int h = 0; h < 2; ++h)
      #pragma unroll
      for (int j = 0; j < 8; ++j) {
        int ci = h*32 + q*8 + j;
        float m  = s2S[ci] * (1.0f / MTOT);
        float v  = s2Q[ci] * (1.0f / MTOT) - m * m;
        float sc = g2[ci] * rsqrtf(v + BN_EPS);
        sc2v[h*8+j] = sc;
        sh2v[h*8+j] = fmaf(-sc, m, be2[ci]);
      }
    bf16x8 a3[8][2];
    #pragma unroll
    for (int t = 0; t < 8; ++t)
      #pragma unroll
      for (int h = 0; h < 2; ++h)
        #pragma unroll
        for (int j = 0; j < 8; ++j)
          a3[t][h][j] = (short)f2bf_bits(W3[(t*16 + i)*64 + h*32 + q*8 + j]);

    float ssum[32], ssq[32];
    if (!FINAL) {
        #pragma unroll
        for (int s = 0; s < 32; ++s) { ssum[s] = 0.f; ssq[s] = 0.f; }
    }
    __syncthreads();

    for (int r16 = 0; r16 < 16; ++r16) {
        const int row = blockIdx.x * 16 + r16;
        const ushort* rp = y2F + row*4096 + wid*1024 + q*128 + i*4;
        uint2 u00 = *(const uint2*)(rp);
        uint2 u01 = *(const uint2*)(rp + 64);
        uint2 u10 = *(const uint2*)(rp + 512);
        uint2 u11 = *(const uint2*)(rp + 576);

        bf16x8 xb[2];
        #pragma unroll
        for (int h = 0; h < 2; ++h) {
            u32 w0 = (h == 0) ? u00.x : u10.x;
            u32 w1 = (h == 0) ? u00.y : u10.y;
            u32 w2 = (h == 0) ? u01.x : u11.x;
            u32 w3 = (h == 0) ? u01.y : u11.y;
            float xf[8];
            xf[0] = __uint_as_float(w0 << 16); xf[1] = __uint_as_float(w0 & 0xffff0000u);
            xf[2] = __uint_as_float(w1 << 16); xf[3] = __uint_as_float(w1 & 0xffff0000u);
            xf[4] = __uint_as_float(w2 << 16); xf[5] = __uint_as_float(w2 & 0xffff0000u);
            xf[6] = __uint_as_float(w3 << 16); xf[7] = __uint_as_float(w3 & 0xffff0000u);
            #pragma unroll
            for (int j = 0; j < 8; ++j) {
                float x = fmaxf(fmaf(sc2v[h*8+j], xf[j], sh2v[h*8+j]), 0.f);
                xb[h][j] = (short)f2bf_bits(x);
            }
        }
        f32x4 acc[8];
        #pragma unroll
        for (int t = 0; t < 8; ++t) acc[t] = (f32x4){0.f,0.f,0.f,0.f};
        #pragma unroll
        for (int t = 0; t < 8; ++t) {
            acc[t] = __builtin_amdgcn_mfma_f32_16x16x32_bf16(a3[t][0], xb[0], acc[t], 0, 0, 0);
            acc[t] = __builtin_amdgcn_mfma_f32_16x16x32_bf16(a3[t][1], xb[1], acc[t], 0, 0, 0);
        }

        if (!FINAL) {
            #pragma unroll
            for (int t = 0; t < 8; ++t)
              #pragma unroll
              for (int reg = 0; reg < 4; ++reg) {
                float y = acc[t][reg];
                ssum[t*4+reg] += y;
                ssq[t*4+reg]  = fmaf(y, y, ssq[t*4+reg]);
              }
        } else {
            float mx = -3.4e38f;
            #pragma unroll
            for (int t = 0; t < 8; ++t) {
                float4 s4 = *(const float4*)&sc3L[t*16 + q*4];
                float4 h4 = *(const float4*)&sh3L[t*16 + q*4];
                mx = fmaxf(mx, fmaf(s4.x, acc[t][0], h4.x));
                mx = fmaxf(mx, fmaf(s4.y, acc[t][1], h4.y));
                mx = fmaxf(mx, fmaf(s4.z, acc[t][2], h4.z));
                mx = fmaxf(mx, fmaf(s4.w, acc[t][3], h4.w));
            }
            mx = fmaxf(mx, __shfl_xor(mx, 16, 64));
            mx = fmaxf(mx, __shfl_xor(mx, 32, 64));
            mx = fmaxf(mx, 0.f);
            if (q == 0) scoreL[r16 & 1][wid*16 + i] = mx;
            __syncthreads();
            if (wid == 0) {
                float sc = scoreL[r16 & 1][l];
                float m2 = sc;
                #pragma unroll
                for (int off = 1; off < 64; off <<= 1) m2 = fmaxf(m2, __shfl_xor(m2, off, 64));
                float e = __expf(sc - m2);
                float se = e;
                #pragma unroll
                for (int off = 1; off < 64; off <<= 1) se += __shfl_xor(se, off, 64);
                float w = e / se;
                const float* gp = grouped + (row*64 + l)*3;
                float ox = w * gp[0], oy = w * gp[1], oz = w * gp[2];
                #pragma unroll
                for (int off = 1; off < 64; off <<= 1) {
                    ox += __shfl_xor(ox, off, 64);
                    oy += __shfl_xor(oy, off, 64);
                    oz += __shfl_xor(oz, off, 64);
                }
                if (l == 0) {
                    int bb = row >> 12, n = row & 4095;
                    outp[bb*3*N_ + 0*N_ + n] = ox;
                    outp[bb*3*N_ + 1*N_ + n] = oy;
                    outp[bb*3*N_ + 2*N_ + n] = oz;
                }
            }
        }
    }

    if (!FINAL) {
        #pragma unroll
        for (int s = 0; s < 32; ++s) {
            #pragma unroll
            for (int off = 1; off < 16; off <<= 1) {
                ssum[s] += __shfl_xor(ssum[s], off, 64);
                ssq[s]  += __shfl_xor(ssq[s],  off, 64);
            }
        }
        if (i == 0) {
            #pragma unroll
            for (int s = 0; s < 32; ++s) {
                int co = (s >> 2)*16 + q*4 + (s & 3);
                atomicAdd(&statS[co], ssum[s]);
                atomicAdd(&statQ[co], ssq[s]);
            }
        }
        __syncthreads();
        if (tid < 128) { atomicAdd(&s3S[tid], statS[tid]); atomicAdd(&s3Q[tid], statQ[tid]); }
    }
}

// ---------------------------------------------------------------------------
extern "C" void kernel_launch(void* const* d_in, const int* in_sizes, int n_in,
                              void* d_out, int out_size, void* d_ws, size_t ws_size,
                              hipStream_t stream)
{
    const float* p1  = (const float*)d_in[0];
    const float* p2  = (const float*)d_in[1];
    // d_in[2] = k (always 32), d_in[3] = t (unused by reference)
    const float* W1  = (const float*)d_in[4];
    const float* b1  = (const float*)d_in[5];
    const float* g1  = (const float*)d_in[6];
    const float* be1 = (const float*)d_in[7];
    const float* W2  = (const float*)d_in[8];
    const float* g2  = (const float*)d_in[10];
    const float* be2 = (const float*)d_in[11];
    const float* W3  = (const float*)d_in[12];
    const float* g3  = (const float*)d_in[14];
    const float* be3 = (const float*)d_in[15];
    // b2 (d_in[9]) and b3 (d_in[13]) cancel through their BatchNorms — unused.

    char* ws = (char*)d_ws;
    const size_t OFF_FEATS   = 4096;
    const size_t OFF_GROUPED = OFF_FEATS + (size_t)MTOT * 4 * 4;        // 16 MB feats
    const size_t OFF_Y2      = OFF_GROUPED + (size_t)MTOT * 3 * 4;      // 12 MB grouped
    const size_t NEEDED      = OFF_Y2 + (size_t)MTOT * 64 * 2;          // 128 MB y2 bf16
    if (ws_size < NEEDED) return;  // fail visibly (wrong output) rather than fault

    float* s1S = (float*)(ws + 0);    float* s1Q = (float*)(ws + 256);
    float* s2S = (float*)(ws + 512);  float* s2Q = (float*)(ws + 768);
    float* s3S = (float*)(ws + 1024); float* s3Q = (float*)(ws + 1536);
    float* feats   = (float*)(ws + OFF_FEATS);
    float* grouped = (float*)(ws + OFF_GROUPED);
    ushort* y2F    = (ushort*)(ws + OFF_Y2);

    hipMemsetAsync(ws, 0, 2048, stream);  // zero all stats accumulators

    knn_kernel<<<1024, 256, 0, stream>>>(p1, p2, feats, grouped);
    stats1_kernel<<<1024, 256, 0, stream>>>(feats, W1, b1, s1S, s1Q);
    conv2_mfma<<<1024, 256, 0, stream>>>(feats, W1, b1, g1, be1, W2,
                                         s1S, s1Q, y2F, s2S, s2Q);
    conv3_mfma<false><<<1024, 256, 0, stream>>>(y2F, g2, be2, W3, g3, be3,
                                                s2S, s2Q, s3S, s3Q, nullptr, nullptr);
    conv3_mfma<true><<<1024, 256, 0, stream>>>(y2F, g2, be2, W3, g3, be3,
                                               s2S, s2Q, s3S, s3Q, grouped,
                                               (float*)d_out);
}

// Round 6
// 549.386 us; speedup vs baseline: 4.2304x; 1.0327x over previous
//
#include <hip/hip_runtime.h>
#include <hip/hip_bf16.h>

// Problem constants (fixed by setup_inputs)
#define B_   4
#define N_   4096
#define KNN_ 32
#define KK_  64          // 2*k
#define MTOT 1048576     // B*N*KK
#define BN_EPS 1e-3f

typedef unsigned int u32;
typedef unsigned long long u64;
typedef __attribute__((ext_vector_type(8))) short bf16x8;
typedef __attribute__((ext_vector_type(4))) float f32x4;

__device__ __forceinline__ ushort f2bf_bits(float f) {   // RNE, finite inputs only
    u32 b = __float_as_uint(f);
    b += 0x7fffu + ((b >> 16) & 1u);
    return (ushort)(b >> 16);
}

// ---------------------------------------------------------------------------
// K1: dual KNN, atomic-free. One wave per query row.
// Round-6 changes: 768-block grid (exactly 3 blocks/CU resident, no tail);
// bisection bracket seeded from [wave-min(k0), wave-max(k3)]; fast-certify
// skips the 64-ballot recount when no lane's kept-4 saturates at T (~87%).
// grid: 768 blocks = 8 (pr,b) * 96 chunks; 42-43 rows/chunk, 4 waves stride.
// ---------------------------------------------------------------------------
__global__ __launch_bounds__(256, 3) void knn_kernel(
    const float* __restrict__ p1, const float* __restrict__ p2,
    float* __restrict__ feats, float* __restrict__ grouped)
{
    __shared__ float2 cxy[N_];                   // 32 KB
    __shared__ float  cz[N_];                    // 16 KB

    const int tid  = threadIdx.x;
    const int wave = tid >> 6, lane = tid & 63;
    const int pb    = blockIdx.x / 96;           // 0..7
    const int chunk = blockIdx.x % 96;
    const int pr = pb >> 2, b = pb & 3;
    const int start = (chunk * 4096) / 96;
    const int end   = ((chunk + 1) * 4096) / 96;

    const float* srcb = (pr ? p2 : p1) + (size_t)b * 3 * N_;
    for (int n = tid; n < N_; n += 256) {
        float x = srcb[n], y = srcb[N_ + n], z = srcb[2*N_ + n];
        cxy[n] = make_float2(x, y);
        cz[n]  = z;
    }
    __syncthreads();

    const float* p1b = p1 + (size_t)b * 3 * N_;
    const u64 below = (1ull << lane) - 1ull;

    for (int n = start + wave; n < end; n += 4) {
        float qx, qy, qz;
        if (pr == 0) { float2 q = cxy[n]; qx = q.x; qy = q.y; qz = cz[n]; }
        else         { qx = p1b[n]; qy = p1b[N_ + n]; qz = p1b[2*N_ + n]; }
        const float s1 = fmaf(qx, qx, fmaf(qy, qy, qz*qz));

        // ---- phase A: keys (once, registers) + sorted kept-4 ----
        u32 keys[64];
        u32 k0 = 0xFFFFFFFFu, k1 = 0xFFFFFFFFu, k2 = 0xFFFFFFFFu, k3 = 0xFFFFFFFFu;
        #pragma unroll
        for (int j = 0; j < 64; ++j) {
            float2 cx2 = cxy[j * 64 + lane];
            float  cz1 = cz[j * 64 + lane];
            float cw  = fmaf(cx2.x, cx2.x, fmaf(cx2.y, cx2.y, cz1*cz1));
            float dot = fmaf(qx, cx2.x, fmaf(qy, cx2.y, qz * cz1));
            float d2  = fmaf(-2.0f, dot, s1 + cw);
            u32 u = __float_as_uint(d2);
            u32 key = u ^ (u32)(((int)u >> 31) | 0x80000000);
            keys[j] = key;
            k3 = min(k3, key);
            u32 t;
            t = min(k2, k3); k3 = max(k2, k3); k2 = t;
            t = min(k1, k2); k2 = max(k1, k2); k1 = t;
            t = min(k0, k1); k1 = max(k0, k1); k0 = t;
        }

        // ---- phase B: bisect rank-31 threshold over kept-4 union ----
        // bracket: T in [wave-min(k0), wave-max(k3)]
        u32 mn = k0, mx = k3;
        #pragma unroll
        for (int off = 1; off < 64; off <<= 1) {
            mn = min(mn, (u32)__shfl_xor((int)mn, off, 64));
            mx = max(mx, (u32)__shfl_xor((int)mx, off, 64));
        }
        u32 lo = mn, hi = mx;
        while (lo < hi) {
            u32 mid = lo + ((hi - lo) >> 1);
            int c = __popcll(__ballot(k0 <= mid)) + __popcll(__ballot(k1 <= mid))
                  + __popcll(__ballot(k2 <= mid)) + __popcll(__ballot(k3 <= mid));
            if (c >= 32) hi = mid; else lo = mid + 1;
        }
        u32 T = lo;

        // ---- phase C: certify. If no lane's kept-4 saturates at T, every
        // key <= T is inside the kept-4 -> nl is exact from 4 ballots. ----
        int nl;
        if (__ballot(k3 <= T) == 0ull) {
            nl = __popcll(__ballot(k0 < T)) + __popcll(__ballot(k1 < T))
               + __popcll(__ballot(k2 < T)) + __popcll(__ballot(k3 < T));
        } else {
            nl = 0;
            #pragma unroll
            for (int j = 0; j < 64; ++j) nl += __popcll(__ballot(keys[j] < T));
            if (nl > 31) {                  // kept-4 truncated the true top-32 (rare)
                lo = 0u; hi = T;
                while (lo < hi) {
                    u32 mid = lo + ((hi - lo) >> 1);
                    int c = 0;
                    #pragma unroll
                    for (int j = 0; j < 64; ++j) c += __popcll(__ballot(keys[j] <= mid));
                    if (c >= 32) hi = mid; else lo = mid + 1;
                }
                T = lo;
                nl = 0;
                #pragma unroll
                for (int j = 0; j < 64; ++j) nl += __popcll(__ballot(keys[j] < T));
            }
        }
        const int need_eq = 32 - nl;        // >= 1; ties resolved by candidate index

        // ---- phase D: emission via ballot prefix (no atomics) ----
        float* fout = feats   + ((size_t)(b * N_ + n) * KK_ + pr * KNN_) * 4;
        float* gout = grouped + ((size_t)(b * N_ + n) * KK_ + pr * KNN_) * 3;
        int base = 0, eq_seen = 0;
        #pragma unroll
        for (int j = 0; j < 64; ++j) {
            u32 key = keys[j];
            bool lt = key < T;
            bool eq = key == T;
            u64 mlt = __ballot(lt);
            u64 meq = __ballot(eq);
            if (mlt | meq) {
                int slot = -1;
                if (lt) slot = base + __popcll(mlt & below);
                else if (eq) {
                    int es = eq_seen + __popcll(meq & below);
                    if (es < need_eq) slot = nl + es;
                }
                if (slot >= 0) {
                    float2 cx2 = cxy[j * 64 + lane];
                    float  cz1 = cz[j * 64 + lane];
                    float rx = cx2.x - qx, ry = cx2.y - qy, rz = cz1 - qz;
                    float dist = sqrtf(fmaf(rx, rx, fmaf(ry, ry, rz*rz)));
                    *(float4*)(fout + slot * 4) = make_float4(rx, ry, rz, dist);
                    gout[slot*3 + 0] = cx2.x; gout[slot*3 + 1] = cx2.y; gout[slot*3 + 2] = cz1;
                }
                base    += __popcll(mlt);
                eq_seen += __popcll(meq);
            }
        }
    }
}

// ---------------------------------------------------------------------------
// K2: stats of y1 = W1@feat + b1 (per-channel sum / sumsq over 1M positions)
// ---------------------------------------------------------------------------
__global__ __launch_bounds__(256) void stats1_kernel(
    const float* __restrict__ feats,
    const float* __restrict__ W1, const float* __restrict__ b1,
    float* __restrict__ s1S, float* __restrict__ s1Q)
{
    __shared__ float4 featL[256];
    __shared__ float red[512];
    const int tid = threadIdx.x;
    const int ch = tid & 63, pg = tid >> 6;
    float w0 = W1[ch*4+0], w1v = W1[ch*4+1];
    float w2v = W1[ch*4+2], w3v = W1[ch*4+3];
    float bb = b1[ch];
    float sum = 0.f, sq = 0.f;
    for (int chunk = 0; chunk < 4; ++chunk) {
        __syncthreads();
        size_t pbase = (size_t)blockIdx.x * 1024 + (size_t)chunk * 256;
        featL[tid] = ((const float4*)feats)[pbase + tid];
        __syncthreads();
        for (int i = 0; i < 64; ++i) {
            float4 f = featL[pg * 64 + i];
            float y = bb + w0*f.x + w1v*f.y + w2v*f.z + w3v*f.w;
            sum += y; sq += y * y;
        }
    }
    red[tid] = sum; red[256 + tid] = sq;
    __syncthreads();
    if (tid < 64) {
        float s = red[tid] + red[64+tid] + red[128+tid] + red[192+tid];
        float q = red[256+tid] + red[320+tid] + red[384+tid] + red[448+tid];
        atomicAdd(&s1S[tid], s);
        atomicAdd(&s1Q[tid], q);
    }
}

// ---------------------------------------------------------------------------
// K3: MFMA conv2 (unchanged)
// ---------------------------------------------------------------------------
__global__ __launch_bounds__(256) void conv2_mfma(
    const float* __restrict__ feats,
    const float* __restrict__ W1, const float* __restrict__ b1,
    const float* __restrict__ g1, const float* __restrict__ be1,
    const float* __restrict__ W2,
    const float* __restrict__ s1S, const float* __restrict__ s1Q,
    ushort* __restrict__ y2F, float* __restrict__ s2S, float* __restrict__ s2Q)
{
    __shared__ float statS[64], statQ[64];
    const int tid = threadIdx.x;
    const int wid = tid >> 6, l = tid & 63, q = l >> 4, i = l & 15;
    if (tid < 64) { statS[tid] = 0.f; statQ[tid] = 0.f; }

    float4 w1f[16];
    float  c1v[16];
    #pragma unroll
    for (int h = 0; h < 2; ++h)
      #pragma unroll
      for (int j = 0; j < 8; ++j) {
        int ci = h*32 + q*8 + j;
        float m  = s1S[ci] * (1.0f / MTOT);
        float v  = s1Q[ci] * (1.0f / MTOT) - m * m;
        float sc = g1[ci] * rsqrtf(v + BN_EPS);
        w1f[h*8+j] = make_float4(sc*W1[ci*4+0], sc*W1[ci*4+1], sc*W1[ci*4+2], sc*W1[ci*4+3]);
        c1v[h*8+j] = fmaf(sc, b1[ci] - m, be1[ci]);
      }
    bf16x8 a2[4][2];
    #pragma unroll
    for (int t = 0; t < 4; ++t)
      #pragma unroll
      for (int h = 0; h < 2; ++h)
        #pragma unroll
        for (int j = 0; j < 8; ++j)
          a2[t][h][j] = (short)f2bf_bits(W2[(t*16 + i)*64 + h*32 + q*8 + j]);

    float ssum[16], ssq[16];
    #pragma unroll
    for (int s = 0; s < 16; ++s) { ssum[s] = 0.f; ssq[s] = 0.f; }
    __syncthreads();

    for (int r16 = 0; r16 < 16; ++r16) {
        const int row = blockIdx.x * 16 + r16;
        float4 f = ((const float4*)feats)[row*64 + wid*16 + i];
        bf16x8 xb[2];
        #pragma unroll
        for (int h = 0; h < 2; ++h)
          #pragma unroll
          for (int j = 0; j < 8; ++j) {
            float4 w = w1f[h*8+j];
            float x = fmaxf(fmaf(w.x, f.x, fmaf(w.y, f.y, fmaf(w.z, f.z, fmaf(w.w, f.w, c1v[h*8+j])))), 0.f);
            xb[h][j] = (short)f2bf_bits(x);
          }
        f32x4 acc[4];
        #pragma unroll
        for (int t = 0; t < 4; ++t) acc[t] = (f32x4){0.f,0.f,0.f,0.f};
        #pragma unroll
        for (int t = 0; t < 4; ++t) {
            acc[t] = __builtin_amdgcn_mfma_f32_16x16x32_bf16(a2[t][0], xb[0], acc[t], 0, 0, 0);
            acc[t] = __builtin_amdgcn_mfma_f32_16x16x32_bf16(a2[t][1], xb[1], acc[t], 0, 0, 0);
        }
        ushort* wp = y2F + row*4096 + wid*1024 + q*64 + i*4;
        #pragma unroll
        for (int t = 0; t < 4; ++t) {
            #pragma unroll
            for (int reg = 0; reg < 4; ++reg) {
                float y = acc[t][reg];
                ssum[t*4+reg] += y;
                ssq[t*4+reg]  = fmaf(y, y, ssq[t*4+reg]);
            }
            uint2 pk;
            pk.x = (u32)f2bf_bits(acc[t][0]) | ((u32)f2bf_bits(acc[t][1]) << 16);
            pk.y = (u32)f2bf_bits(acc[t][2]) | ((u32)f2bf_bits(acc[t][3]) << 16);
            *(uint2*)(wp + t*256) = pk;
        }
    }
    #pragma unroll
    for (int s = 0; s < 16; ++s) {
        #pragma unroll
        for (int off = 1; off < 16; off <<= 1) {
            ssum[s] += __shfl_xor(ssum[s], off, 64);
            ssq[s]  += __shfl_xor(ssq[s],  off, 64);
        }
    }
    if (i == 0) {
        #pragma unroll
        for (int s = 0; s < 16; ++s) {
            int co = (s >> 2)*16 + q*4 + (s & 3);
            atomicAdd(&statS[co], ssum[s]);
            atomicAdd(&statQ[co], ssq[s]);
        }
    }
    __syncthreads();
    if (tid < 64) { atomicAdd(&s2S[tid], statS[tid]); atomicAdd(&s2Q[tid], statQ[tid]); }
}

// ---------------------------------------------------------------------------
// K4/K5: MFMA conv3 (unchanged)
// ---------------------------------------------------------------------------
template<bool FINAL>
__global__ __launch_bounds__(256) void conv3_mfma(
    const ushort* __restrict__ y2F,
    const float* __restrict__ g2, const float* __restrict__ be2,
    const float* __restrict__ W3,
    const float* __restrict__ g3, const float* __restrict__ be3,
    const float* __restrict__ s2S, const float* __restrict__ s2Q,
    float* __restrict__ s3S, float* __restrict__ s3Q,
    const float* __restrict__ grouped, float* __restrict__ outp)
{
    __shared__ float statS[128], statQ[128];
    __shared__ float sc3L[128], sh3L[128];
    __shared__ float scoreL[2][64];

    const int tid = threadIdx.x;
    const int wid = tid >> 6, l = tid & 63, q = l >> 4, i = l & 15;

    if (!FINAL) {
        if (tid < 128) { statS[tid] = 0.f; statQ[tid] = 0.f; }
    } else if (tid < 128) {
        float m  = s3S[tid] * (1.0f / MTOT);
        float v  = s3Q[tid] * (1.0f / MTOT) - m * m;
        float sc = g3[tid] * rsqrtf(v + BN_EPS);
        sc3L[tid] = sc;
        sh3L[tid] = fmaf(-sc, m, be3[tid]);
    }

    float sc2v[16], sh2v[16];
    #pragma unroll
    for (int h = 0; h < 2; ++h)
      #pragma unroll
      for (int j = 0; j < 8; ++j) {
        int ci = h*32 + q*8 + j;
        float m  = s2S[ci] * (1.0f / MTOT);
        float v  = s2Q[ci] * (1.0f / MTOT) - m * m;
        float sc = g2[ci] * rsqrtf(v + BN_EPS);
        sc2v[h*8+j] = sc;
        sh2v[h*8+j] = fmaf(-sc, m, be2[ci]);
      }
    bf16x8 a3[8][2];
    #pragma unroll
    for (int t = 0; t < 8; ++t)
      #pragma unroll
      for (int h = 0; h < 2; ++h)
        #pragma unroll
        for (int j = 0; j < 8; ++j)
          a3[t][h][j] = (short)f2bf_bits(W3[(t*16 + i)*64 + h*32 + q*8 + j]);

    float ssum[32], ssq[32];
    if (!FINAL) {
        #pragma unroll
        for (int s = 0; s < 32; ++s) { ssum[s] = 0.f; ssq[s] = 0.f; }
    }
    __syncthreads();

    for (int r16 = 0; r16 < 16; ++r16) {
        const int row = blockIdx.x * 16 + r16;
        const ushort* rp = y2F + row*4096 + wid*1024 + q*128 + i*4;
        uint2 u00 = *(const uint2*)(rp);
        uint2 u01 = *(const uint2*)(rp + 64);
        uint2 u10 = *(const uint2*)(rp + 512);
        uint2 u11 = *(const uint2*)(rp + 576);

        bf16x8 xb[2];
        #pragma unroll
        for (int h = 0; h < 2; ++h) {
            u32 w0 = (h == 0) ? u00.x : u10.x;
            u32 w1 = (h == 0) ? u00.y : u10.y;
            u32 w2 = (h == 0) ? u01.x : u11.x;
            u32 w3 = (h == 0) ? u01.y : u11.y;
            float xf[8];
            xf[0] = __uint_as_float(w0 << 16); xf[1] = __uint_as_float(w0 & 0xffff0000u);
            xf[2] = __uint_as_float(w1 << 16); xf[3] = __uint_as_float(w1 & 0xffff0000u);
            xf[4] = __uint_as_float(w2 << 16); xf[5] = __uint_as_float(w2 & 0xffff0000u);
            xf[6] = __uint_as_float(w3 << 16); xf[7] = __uint_as_float(w3 & 0xffff0000u);
            #pragma unroll
            for (int j = 0; j < 8; ++j) {
                float x = fmaxf(fmaf(sc2v[h*8+j], xf[j], sh2v[h*8+j]), 0.f);
                xb[h][j] = (short)f2bf_bits(x);
            }
        }
        f32x4 acc[8];
        #pragma unroll
        for (int t = 0; t < 8; ++t) acc[t] = (f32x4){0.f,0.f,0.f,0.f};
        #pragma unroll
        for (int t = 0; t < 8; ++t) {
            acc[t] = __builtin_amdgcn_mfma_f32_16x16x32_bf16(a3[t][0], xb[0], acc[t], 0, 0, 0);
            acc[t] = __builtin_amdgcn_mfma_f32_16x16x32_bf16(a3[t][1], xb[1], acc[t], 0, 0, 0);
        }

        if (!FINAL) {
            #pragma unroll
            for (int t = 0; t < 8; ++t)
              #pragma unroll
              for (int reg = 0; reg < 4; ++reg) {
                float y = acc[t][reg];
                ssum[t*4+reg] += y;
                ssq[t*4+reg]  = fmaf(y, y, ssq[t*4+reg]);
              }
        } else {
            float mx = -3.4e38f;
            #pragma unroll
            for (int t = 0; t < 8; ++t) {
                float4 s4 = *(const float4*)&sc3L[t*16 + q*4];
                float4 h4 = *(const float4*)&sh3L[t*16 + q*4];
                mx = fmaxf(mx, fmaf(s4.x, acc[t][0], h4.x));
                mx = fmaxf(mx, fmaf(s4.y, acc[t][1], h4.y));
                mx = fmaxf(mx, fmaf(s4.z, acc[t][2], h4.z));
                mx = fmaxf(mx, fmaf(s4.w, acc[t][3], h4.w));
            }
            mx = fmaxf(mx, __shfl_xor(mx, 16, 64));
            mx = fmaxf(mx, __shfl_xor(mx, 32, 64));
            mx = fmaxf(mx, 0.f);
            if (q == 0) scoreL[r16 & 1][wid*16 + i] = mx;
            __syncthreads();
            if (wid == 0) {
                float sc = scoreL[r16 & 1][l];
                float m2 = sc;
                #pragma unroll
                for (int off = 1; off < 64; off <<= 1) m2 = fmaxf(m2, __shfl_xor(m2, off, 64));
                float e = __expf(sc - m2);
                float se = e;
                #pragma unroll
                for (int off = 1; off < 64; off <<= 1) se += __shfl_xor(se, off, 64);
                float w = e / se;
                const float* gp = grouped + (row*64 + l)*3;
                float ox = w * gp[0], oy = w * gp[1], oz = w * gp[2];
                #pragma unroll
                for (int off = 1; off < 64; off <<= 1) {
                    ox += __shfl_xor(ox, off, 64);
                    oy += __shfl_xor(oy, off, 64);
                    oz += __shfl_xor(oz, off, 64);
                }
                if (l == 0) {
                    int bb = row >> 12, n = row & 4095;
                    outp[bb*3*N_ + 0*N_ + n] = ox;
                    outp[bb*3*N_ + 1*N_ + n] = oy;
                    outp[bb*3*N_ + 2*N_ + n] = oz;
                }
            }
        }
    }

    if (!FINAL) {
        #pragma unroll
        for (int s = 0; s < 32; ++s) {
            #pragma unroll
            for (int off = 1; off < 16; off <<= 1) {
                ssum[s] += __shfl_xor(ssum[s], off, 64);
                ssq[s]  += __shfl_xor(ssq[s],  off, 64);
            }
        }
        if (i == 0) {
            #pragma unroll
            for (int s = 0; s < 32; ++s) {
                int co = (s >> 2)*16 + q*4 + (s & 3);
                atomicAdd(&statS[co], ssum[s]);
                atomicAdd(&statQ[co], ssq[s]);
            }
        }
        __syncthreads();
        if (tid < 128) { atomicAdd(&s3S[tid], statS[tid]); atomicAdd(&s3Q[tid], statQ[tid]); }
    }
}

// ---------------------------------------------------------------------------
extern "C" void kernel_launch(void* const* d_in, const int* in_sizes, int n_in,
                              void* d_out, int out_size, void* d_ws, size_t ws_size,
                              hipStream_t stream)
{
    const float* p1  = (const float*)d_in[0];
    const float* p2  = (const float*)d_in[1];
    // d_in[2] = k (always 32), d_in[3] = t (unused by reference)
    const float* W1  = (const float*)d_in[4];
    const float* b1  = (const float*)d_in[5];
    const float* g1  = (const float*)d_in[6];
    const float* be1 = (const float*)d_in[7];
    const float* W2  = (const float*)d_in[8];
    const float* g2  = (const float*)d_in[10];
    const float* be2 = (const float*)d_in[11];
    const float* W3  = (const float*)d_in[12];
    const float* g3  = (const float*)d_in[14];
    const float* be3 = (const float*)d_in[15];
    // b2 (d_in[9]) and b3 (d_in[13]) cancel through their BatchNorms — unused.

    char* ws = (char*)d_ws;
    const size_t OFF_FEATS   = 4096;
    const size_t OFF_GROUPED = OFF_FEATS + (size_t)MTOT * 4 * 4;        // 16 MB feats
    const size_t OFF_Y2      = OFF_GROUPED + (size_t)MTOT * 3 * 4;      // 12 MB grouped
    const size_t NEEDED      = OFF_Y2 + (size_t)MTOT * 64 * 2;          // 128 MB y2 bf16
    if (ws_size < NEEDED) return;  // fail visibly (wrong output) rather than fault

    float* s1S = (float*)(ws + 0);    float* s1Q = (float*)(ws + 256);
    float* s2S = (float*)(ws + 512);  float* s2Q = (float*)(ws + 768);
    float* s3S = (float*)(ws + 1024); float* s3Q = (float*)(ws + 1536);
    float* feats   = (float*)(ws + OFF_FEATS);
    float* grouped = (float*)(ws + OFF_GROUPED);
    ushort* y2F    = (ushort*)(ws + OFF_Y2);

    hipMemsetAsync(ws, 0, 2048, stream);  // zero all stats accumulators

    knn_kernel<<<768, 256, 0, stream>>>(p1, p2, feats, grouped);
    stats1_kernel<<<1024, 256, 0, stream>>>(feats, W1, b1, s1S, s1Q);
    conv2_mfma<<<1024, 256, 0, stream>>>(feats, W1, b1, g1, be1, W2,
                                         s1S, s1Q, y2F, s2S, s2Q);
    conv3_mfma<false><<<1024, 256, 0, stream>>>(y2F, g2, be2, W3, g3, be3,
                                                s2S, s2Q, s3S, s3Q, nullptr, nullptr);
    conv3_mfma<true><<<1024, 256, 0, stream>>>(y2F, g2, be2, W3, g3, be3,
                                               s2S, s2Q, s3S, s3Q, grouped,
                                               (float*)d_out);
}